// Round 1
// baseline (771.728 us; speedup 1.0000x reference)
//
#include <hip/hip_runtime.h>
#include <math.h>

#define T_    3
#define RES_  24
#define DIM_  768
#define HEADS_ 16
#define DH_   48
#define EMB_  1024
#define HW_   576            // RES*RES
#define THW_  1728           // T*HW
#define MLP_  3072
#define NF_   5376           // 3*DIM + MLP
#define EPS_  1e-5f

__device__ __forceinline__ float siluf(float x) { return x / (1.f + expf(-x)); }

// ---------------------------------------------------------------------------
// K1: mod[t][j] = silu(emb[t]) @ w_mod + b_mod   (3 x 1536)
// grid (12 col-chunks of 128, 3 t), block 256 (2 k-halves x 128 cols)
// ---------------------------------------------------------------------------
__global__ __launch_bounds__(256) void mod_kernel(
    const float* __restrict__ emb, const float* __restrict__ w_mod,
    const float* __restrict__ b_mod, float* __restrict__ mod)
{
    int t = blockIdx.y;
    int chunk = blockIdx.x;
    __shared__ float se[EMB_];
    __shared__ float part[128];
    int tid = threadIdx.x;
    for (int i = tid; i < EMB_; i += 256) {
        float e = emb[t * EMB_ + i];
        se[i] = e / (1.f + expf(-e));
    }
    __syncthreads();
    int r = tid >> 7;           // 0..1  (k-half)
    int c = tid & 127;
    int j = chunk * 128 + c;
    const float* wp = w_mod + j;
    float acc = 0.f;
    for (int e = r * 512; e < r * 512 + 512; ++e)
        acc += se[e] * wp[e * 1536];
    if (r == 1) part[c] = acc;
    __syncthreads();
    if (r == 0)
        mod[t * 1536 + j] = acc + part[c] + b_mod[j];
}

// ---------------------------------------------------------------------------
// K2: h[m][c] = LN(x[t,:,hw])[c] * (1+scale[t,c]) + shift[t,c]
// one block (256 thr) per token m
// ---------------------------------------------------------------------------
__global__ __launch_bounds__(256) void ln_mod_kernel(
    const float* __restrict__ x, const float* __restrict__ mod,
    float* __restrict__ h)
{
    int m = blockIdx.x;
    int t = m / HW_;
    int hw = m - t * HW_;
    const float* xp = x + (size_t)t * DIM_ * HW_ + hw;
    int tid = threadIdx.x;
    float v0 = xp[(size_t)tid * HW_];
    float v1 = xp[(size_t)(tid + 256) * HW_];
    float v2 = xp[(size_t)(tid + 512) * HW_];
    float s  = v0 + v1 + v2;
    float sq = v0 * v0 + v1 * v1 + v2 * v2;
#pragma unroll
    for (int off = 32; off > 0; off >>= 1) {
        s  += __shfl_xor(s, off, 64);
        sq += __shfl_xor(sq, off, 64);
    }
    __shared__ float ssum[4], ssq[4];
    int lane = tid & 63, wid = tid >> 6;
    if (lane == 0) { ssum[wid] = s; ssq[wid] = sq; }
    __syncthreads();
    float tot  = ssum[0] + ssum[1] + ssum[2] + ssum[3];
    float totq = ssq[0] + ssq[1] + ssq[2] + ssq[3];
    float mean = tot * (1.f / 768.f);
    float var  = totq * (1.f / 768.f) - mean * mean;
    float rs = rsqrtf(var + EPS_);
    const float* sc = mod + t * 1536;
    const float* sh = sc + 768;
    float* hp = h + (size_t)m * DIM_;
    hp[tid]       = (v0 - mean) * rs * (1.f + sc[tid])       + sh[tid];
    hp[tid + 256] = (v1 - mean) * rs * (1.f + sc[tid + 256]) + sh[tid + 256];
    hp[tid + 512] = (v2 - mean) * rs * (1.f + sc[tid + 512]) + sh[tid + 512];
}

// ---------------------------------------------------------------------------
// K3: fused = h @ W_fused + b_fused   M=1728 K=768 N=5376
// 64x64 tile, BK=16, 256 threads, 4x4 micro-tile
// ---------------------------------------------------------------------------
__global__ __launch_bounds__(256) void gemm_fused_kernel(
    const float* __restrict__ A, const float* __restrict__ B,
    const float* __restrict__ bias, float* __restrict__ C)
{
    const int K = DIM_, N = NF_;
    __shared__ float As[16][68];
    __shared__ float Bs[16][68];
    int bm = blockIdx.y * 64, bn = blockIdx.x * 64;
    int tid = threadIdx.x;
    int tx = tid & 15, ty = tid >> 4;
    int ar = tid >> 2, ak = (tid & 3) * 4;
    int br = tid >> 4, bc = (tid & 15) * 4;
    float acc[4][4] = {};
    for (int k0 = 0; k0 < K; k0 += 16) {
        float4 av = *(const float4*)(A + (size_t)(bm + ar) * K + k0 + ak);
        As[ak + 0][ar] = av.x; As[ak + 1][ar] = av.y;
        As[ak + 2][ar] = av.z; As[ak + 3][ar] = av.w;
        float4 bv = *(const float4*)(B + (size_t)(k0 + br) * N + bn + bc);
        *(float4*)&Bs[br][bc] = bv;
        __syncthreads();
#pragma unroll
        for (int kk = 0; kk < 16; ++kk) {
            float4 a = *(const float4*)&As[kk][ty * 4];
            float4 b = *(const float4*)&Bs[kk][tx * 4];
            float ai[4] = {a.x, a.y, a.z, a.w};
            float bj[4] = {b.x, b.y, b.z, b.w};
#pragma unroll
            for (int i = 0; i < 4; ++i)
#pragma unroll
                for (int j = 0; j < 4; ++j)
                    acc[i][j] += ai[i] * bj[j];
        }
        __syncthreads();
    }
#pragma unroll
    for (int i = 0; i < 4; ++i) {
        int mrow = bm + ty * 4 + i;
#pragma unroll
        for (int j = 0; j < 4; ++j) {
            int ncol = bn + tx * 4 + j;
            C[(size_t)mrow * N + ncol] = acc[i][j] + bias[ncol];
        }
    }
}

// ---------------------------------------------------------------------------
// K4: per (head, token) wave: LN(q), LN(k) over DH=48, RoPE, q*=1/sqrt(48)
// ---------------------------------------------------------------------------
__global__ __launch_bounds__(256) void qkln_rope_kernel(
    const float* __restrict__ fused,
    const float* __restrict__ qn_w, const float* __restrict__ qn_b,
    const float* __restrict__ kn_w, const float* __restrict__ kn_b,
    float* __restrict__ qb, float* __restrict__ kb)
{
    int tid = threadIdx.x;
    int lane = tid & 63, wid = tid >> 6;
    int idx = blockIdx.x * 4 + wid;       // 0 .. 27647
    int head = idx / THW_;
    int m = idx - head * THW_;
    const float* fp = fused + (size_t)m * NF_ + head * DH_;
    float qv = 0.f, kv = 0.f;
    if (lane < DH_) { qv = fp[lane]; kv = fp[768 + lane]; }
    float s = qv, sq = qv * qv, sk = kv, sqk = kv * kv;
#pragma unroll
    for (int off = 32; off > 0; off >>= 1) {
        s   += __shfl_xor(s, off, 64);
        sq  += __shfl_xor(sq, off, 64);
        sk  += __shfl_xor(sk, off, 64);
        sqk += __shfl_xor(sqk, off, 64);
    }
    float mq = s  * (1.f / 48.f), vq = sq  * (1.f / 48.f) - mq * mq;
    float mk = sk * (1.f / 48.f), vk = sqk * (1.f / 48.f) - mk * mk;
    float qn = 0.f, kn = 0.f;
    if (lane < DH_) {
        qn = (qv - mq) * rsqrtf(vq + EPS_) * qn_w[lane] + qn_b[lane];
        kn = (kv - mk) * rsqrtf(vk + EPS_) * kn_w[lane] + kn_b[lane];
    }
    // RoPE: pair (2i, 2i+1); angle i: grp=i/8 picks {t,h,w}, j=i%8 freq
    int t = m / HW_; int hw = m - t * HW_;
    int hh = hw / RES_; int ww = hw - hh * RES_;
    int i = lane >> 1;
    int grp = i >> 3, j = i & 7;
    float pos = (grp == 0) ? (float)t : (grp == 1) ? (float)hh : (float)ww;
    float invf = powf(10000.f, -(float)j * (2.f / 16.f));
    float ang = pos * invf;
    float cs = cosf(ang), sn = sinf(ang);
    float qp = __shfl_xor(qn, 1, 64);
    float kp = __shfl_xor(kn, 1, 64);
    float qo, ko;
    if ((lane & 1) == 0) { qo = qn * cs - qp * sn; ko = kn * cs - kp * sn; }
    else                 { qo = qp * sn + qn * cs; ko = kp * sn + kn * cs; }
    if (lane < DH_) {
        size_t o = ((size_t)head * THW_ + m) * DH_ + lane;
        qb[o] = qo * 0.14433756729740643f;   // * DH^-0.5
        kb[o] = ko;
    }
}

// ---------------------------------------------------------------------------
// K5: neighborhood attention, one wave per (head, token); 75 neighbors
// v read directly from fused[:, 1536 + head*48 + d]
// ---------------------------------------------------------------------------
__global__ __launch_bounds__(256) void attn_kernel(
    const float* __restrict__ qb, const float* __restrict__ kb,
    const float* __restrict__ fused, float* __restrict__ xa)
{
    int tid = threadIdx.x;
    int lane = tid & 63, wid = tid >> 6;
    int idx = blockIdx.x * 4 + wid;
    int head = idx / THW_;
    int m = idx - head * THW_;
    int t = m / HW_; int hw = m - t * HW_;
    int hh = hw / RES_; int ww = hw - hh * RES_;
    int hs = min(max(hh - 2, 0), RES_ - 5);
    int wstart = min(max(ww - 2, 0), RES_ - 5);
    (void)t;
    __shared__ float qs[4][48];
    __shared__ float ps[4][80];
    if (lane < 48) qs[wid][lane] = qb[((size_t)head * THW_ + m) * DH_ + lane];
    __syncthreads();
    // scores: jj = lane (all 64 < 75) and jj = lane+64 (lanes 0..10)
    float s0, s1 = -1e30f;
    {
        int jj = lane;
        int a = jj / 25, rem = jj - a * 25, c = rem / 5, e = rem - c * 5;
        int nm = a * HW_ + (hs + c) * RES_ + (wstart + e);
        const float* kp = kb + ((size_t)head * THW_ + nm) * DH_;
        float acc = 0.f;
#pragma unroll
        for (int d = 0; d < 48; ++d) acc += qs[wid][d] * kp[d];
        s0 = acc;
    }
    if (lane < 11) {
        int jj = lane + 64;
        int a = jj / 25, rem = jj - a * 25, c = rem / 5, e = rem - c * 5;
        int nm = a * HW_ + (hs + c) * RES_ + (wstart + e);
        const float* kp = kb + ((size_t)head * THW_ + nm) * DH_;
        float acc = 0.f;
#pragma unroll
        for (int d = 0; d < 48; ++d) acc += qs[wid][d] * kp[d];
        s1 = acc;
    }
    float mx = fmaxf(s0, s1);
#pragma unroll
    for (int off = 32; off > 0; off >>= 1) mx = fmaxf(mx, __shfl_xor(mx, off, 64));
    float p0 = expf(s0 - mx);
    float p1 = (lane < 11) ? expf(s1 - mx) : 0.f;
    float sum = p0 + p1;
#pragma unroll
    for (int off = 32; off > 0; off >>= 1) sum += __shfl_xor(sum, off, 64);
    float invs = 1.f / sum;
    ps[wid][lane] = p0 * invs;
    if (lane < 11) ps[wid][lane + 64] = p1 * invs;
    __syncthreads();
    if (lane < 48) {
        float acc = 0.f;
        const float* vbase = fused + 1536 + head * DH_ + lane;
        int j = 0;
        for (int a = 0; a < 3; ++a)
            for (int c = 0; c < 5; ++c) {
                int rowbase = a * HW_ + (hs + c) * RES_ + wstart;
#pragma unroll
                for (int e = 0; e < 5; ++e) {
                    acc += ps[wid][j] * vbase[(size_t)(rowbase + e) * NF_];
                    ++j;
                }
            }
        xa[(size_t)m * DIM_ + head * DH_ + lane] = acc;
    }
}

// ---------------------------------------------------------------------------
// K6: out = x + xa @ W_out + silu(mlp_h) @ W_mlp + b_mlp
// merged K=3840 GEMM; output written in (t, c, hw) layout = skip layout
// ---------------------------------------------------------------------------
__global__ __launch_bounds__(256) void gemm_out_kernel(
    const float* __restrict__ xa, const float* __restrict__ fused,
    const float* __restrict__ W_out, const float* __restrict__ W_mlp,
    const float* __restrict__ b_mlp, const float* __restrict__ x,
    float* __restrict__ out)
{
    __shared__ float As[16][68];
    __shared__ float Bs[16][68];
    int bm = blockIdx.y * 64, bn = blockIdx.x * 64;
    int tid = threadIdx.x;
    int tx = tid & 15, ty = tid >> 4;
    int ar = tid >> 2, ak = (tid & 3) * 4;
    int br = tid >> 4, bc = (tid & 15) * 4;
    float acc[4][4] = {};
    for (int k0 = 0; k0 < 3840; k0 += 16) {
        float4 av;
        if (k0 < 768) {
            av = *(const float4*)(xa + (size_t)(bm + ar) * 768 + k0 + ak);
        } else {
            av = *(const float4*)(fused + (size_t)(bm + ar) * NF_ + 2304 + (k0 - 768) + ak);
            av.x = siluf(av.x); av.y = siluf(av.y);
            av.z = siluf(av.z); av.w = siluf(av.w);
        }
        As[ak + 0][ar] = av.x; As[ak + 1][ar] = av.y;
        As[ak + 2][ar] = av.z; As[ak + 3][ar] = av.w;
        const float* Bsrc = (k0 < 768)
            ? (W_out + (size_t)(k0 + br) * 768)
            : (W_mlp + (size_t)(k0 - 768 + br) * 768);
        float4 bv = *(const float4*)(Bsrc + bn + bc);
        *(float4*)&Bs[br][bc] = bv;
        __syncthreads();
#pragma unroll
        for (int kk = 0; kk < 16; ++kk) {
            float4 a = *(const float4*)&As[kk][ty * 4];
            float4 b = *(const float4*)&Bs[kk][tx * 4];
            float ai[4] = {a.x, a.y, a.z, a.w};
            float bj[4] = {b.x, b.y, b.z, b.w};
#pragma unroll
            for (int i = 0; i < 4; ++i)
#pragma unroll
                for (int j = 0; j < 4; ++j)
                    acc[i][j] += ai[i] * bj[j];
        }
        __syncthreads();
    }
#pragma unroll
    for (int i = 0; i < 4; ++i) {
        int mrow = bm + ty * 4 + i;
        int tt = mrow / HW_;
        int hw = mrow - tt * HW_;
#pragma unroll
        for (int j = 0; j < 4; ++j) {
            int ncol = bn + tx * 4 + j;
            size_t oidx = (size_t)tt * DIM_ * HW_ + (size_t)ncol * HW_ + hw;
            out[oidx] = x[oidx] + acc[i][j] + b_mlp[ncol];
        }
    }
}

// ---------------------------------------------------------------------------
extern "C" void kernel_launch(void* const* d_in, const int* in_sizes, int n_in,
                              void* d_out, int out_size, void* d_ws, size_t ws_size,
                              hipStream_t stream) {
    const float* x       = (const float*)d_in[0];
    const float* emb     = (const float*)d_in[1];
    const float* w_mod   = (const float*)d_in[2];
    const float* b_mod   = (const float*)d_in[3];
    const float* qn_w    = (const float*)d_in[4];
    const float* qn_b    = (const float*)d_in[5];
    const float* kn_w    = (const float*)d_in[6];
    const float* kn_b    = (const float*)d_in[7];
    const float* W_fused = (const float*)d_in[8];
    const float* b_fused = (const float*)d_in[9];
    const float* W_out   = (const float*)d_in[10];
    const float* W_mlp   = (const float*)d_in[11];
    const float* b_mlp   = (const float*)d_in[12];
    float* out = (float*)d_out;

    float* ws    = (float*)d_ws;
    float* mod   = ws;                      // 3*1536          = 4608
    float* h     = mod + 4608;              // 1728*768        = 1327104
    float* fused = h + 1327104;             // 1728*5376       = 9289728
    float* qb    = fused + 9289728;         // 16*1728*48      = 1327104
    float* kb    = qb + 1327104;            // 1327104
    float* xa    = kb + 1327104;            // 1327104

    mod_kernel<<<dim3(12, 3), 256, 0, stream>>>(emb, w_mod, b_mod, mod);
    ln_mod_kernel<<<THW_, 256, 0, stream>>>(x, mod, h);
    gemm_fused_kernel<<<dim3(NF_ / 64, THW_ / 64), 256, 0, stream>>>(h, W_fused, b_fused, fused);
    qkln_rope_kernel<<<(HEADS_ * THW_) / 4, 256, 0, stream>>>(fused, qn_w, qn_b, kn_w, kn_b, qb, kb);
    attn_kernel<<<(HEADS_ * THW_) / 4, 256, 0, stream>>>(qb, kb, fused, xa);
    gemm_out_kernel<<<dim3(DIM_ / 64, THW_ / 64), 256, 0, stream>>>(xa, fused, W_out, W_mlp, b_mlp, x, out);
}

// Round 2
// 365.331 us; speedup vs baseline: 2.1124x; 2.1124x over previous
//
#include <hip/hip_runtime.h>
#include <hip/hip_bf16.h>
#include <math.h>

#define T_    3
#define RES_  24
#define DIM_  768
#define HEADS_ 16
#define DH_   48
#define EMB_  1024
#define HW_   576            // RES*RES
#define THW_  1728           // T*HW
#define MP_   1792           // THW padded to multiple of 128
#define MLP_  3072
#define NF_   5376           // 3*DIM + MLP
#define QKV_  2304           // 3*DIM
#define KTOT_ 3840           // DIM + MLP (second GEMM K)
#define EPS_  1e-5f

typedef __attribute__((ext_vector_type(8))) short bf16x8;
typedef __attribute__((ext_vector_type(4))) float f32x4;

__device__ __forceinline__ float siluf(float x) { return x / (1.f + expf(-x)); }

__device__ __forceinline__ unsigned short f2bf(float f) {
    __hip_bfloat16 b = __float2bfloat16(f);
    return *reinterpret_cast<unsigned short*>(&b);
}

__device__ __forceinline__ void async_copy16(const void* g, void* l) {
    __builtin_amdgcn_global_load_lds(
        (__attribute__((address_space(1))) void*)g,
        (__attribute__((address_space(3))) void*)l,
        16, 0, 0);
}

// ---------------------------------------------------------------------------
// K0a: W_fused (768 x 5376 f32) -> Bt1 (5376 x 768 bf16)   [transposed]
// ---------------------------------------------------------------------------
__global__ __launch_bounds__(256) void conv_wfused_kernel(
    const float* __restrict__ W, unsigned short* __restrict__ Wt)
{
    __shared__ float tile[32][33];
    int n0 = blockIdx.x * 32;           // 0..5375
    int k0 = blockIdx.y * 32;           // 0..767
    int c = threadIdx.x & 31;
    int r = threadIdx.x >> 5;           // 0..7
#pragma unroll
    for (int i = 0; i < 4; ++i)
        tile[r + 8 * i][c] = W[(size_t)(k0 + r + 8 * i) * NF_ + n0 + c];
    __syncthreads();
#pragma unroll
    for (int i = 0; i < 4; ++i)
        Wt[(size_t)(n0 + r + 8 * i) * DIM_ + k0 + c] = f2bf(tile[c][r + 8 * i]);
}

// ---------------------------------------------------------------------------
// K0b: [W_out;W_mlp] (3840 x 768 f32) -> Bt2 (768 x 3840 bf16)  [transposed]
// ---------------------------------------------------------------------------
__global__ __launch_bounds__(256) void conv_wcat_kernel(
    const float* __restrict__ W_out, const float* __restrict__ W_mlp,
    unsigned short* __restrict__ Wt)
{
    __shared__ float tile[32][33];
    int k0 = blockIdx.x * 32;           // 0..3839
    int n0 = blockIdx.y * 32;           // 0..767
    int c = threadIdx.x & 31;
    int r = threadIdx.x >> 5;
#pragma unroll
    for (int i = 0; i < 4; ++i) {
        int k = k0 + r + 8 * i;
        float v = (k < DIM_) ? W_out[(size_t)k * DIM_ + n0 + c]
                             : W_mlp[(size_t)(k - DIM_) * DIM_ + n0 + c];
        tile[r + 8 * i][c] = v;
    }
    __syncthreads();
#pragma unroll
    for (int i = 0; i < 4; ++i)
        Wt[(size_t)(n0 + r + 8 * i) * KTOT_ + k0 + c] = f2bf(tile[c][r + 8 * i]);
}

// ---------------------------------------------------------------------------
// K1: mod[t][j] = silu(emb[t]) @ w_mod + b_mod   (3 x 1536)
// ---------------------------------------------------------------------------
__global__ __launch_bounds__(256) void mod_kernel(
    const float* __restrict__ emb, const float* __restrict__ w_mod,
    const float* __restrict__ b_mod, float* __restrict__ mod)
{
    int t = blockIdx.y;
    int chunk = blockIdx.x;
    __shared__ float se[EMB_];
    __shared__ float part[128];
    int tid = threadIdx.x;
    for (int i = tid; i < EMB_; i += 256) {
        float e = emb[t * EMB_ + i];
        se[i] = e / (1.f + expf(-e));
    }
    __syncthreads();
    int r = tid >> 7;
    int c = tid & 127;
    int j = chunk * 128 + c;
    const float* wp = w_mod + j;
    float acc = 0.f;
    for (int e = r * 512; e < r * 512 + 512; ++e)
        acc += se[e] * wp[e * 1536];
    if (r == 1) part[c] = acc;
    __syncthreads();
    if (r == 0)
        mod[t * 1536 + j] = acc + part[c] + b_mod[j];
}

// ---------------------------------------------------------------------------
// K2: h[m][c] = bf16( LN(x[t,:,hw])[c] * (1+scale[t,c]) + shift[t,c] )
// ---------------------------------------------------------------------------
__global__ __launch_bounds__(256) void ln_mod_kernel(
    const float* __restrict__ x, const float* __restrict__ mod,
    unsigned short* __restrict__ h)
{
    int m = blockIdx.x;
    int t = m / HW_;
    int hw = m - t * HW_;
    const float* xp = x + (size_t)t * DIM_ * HW_ + hw;
    int tid = threadIdx.x;
    float v0 = xp[(size_t)tid * HW_];
    float v1 = xp[(size_t)(tid + 256) * HW_];
    float v2 = xp[(size_t)(tid + 512) * HW_];
    float s  = v0 + v1 + v2;
    float sq = v0 * v0 + v1 * v1 + v2 * v2;
#pragma unroll
    for (int off = 32; off > 0; off >>= 1) {
        s  += __shfl_xor(s, off, 64);
        sq += __shfl_xor(sq, off, 64);
    }
    __shared__ float ssum[4], ssq[4];
    int lane = tid & 63, wid = tid >> 6;
    if (lane == 0) { ssum[wid] = s; ssq[wid] = sq; }
    __syncthreads();
    float tot  = ssum[0] + ssum[1] + ssum[2] + ssum[3];
    float totq = ssq[0] + ssq[1] + ssq[2] + ssq[3];
    float mean = tot * (1.f / 768.f);
    float var  = totq * (1.f / 768.f) - mean * mean;
    float rs = rsqrtf(var + EPS_);
    const float* sc = mod + t * 1536;
    const float* sh = sc + 768;
    unsigned short* hp = h + (size_t)m * DIM_;
    hp[tid]       = f2bf((v0 - mean) * rs * (1.f + sc[tid])       + sh[tid]);
    hp[tid + 256] = f2bf((v1 - mean) * rs * (1.f + sc[tid + 256]) + sh[tid + 256]);
    hp[tid + 512] = f2bf((v2 - mean) * rs * (1.f + sc[tid + 512]) + sh[tid + 512]);
}

// ---------------------------------------------------------------------------
// K3: MFMA GEMM1: C = h(1792x768) @ Bt1^T(5376x768) + b_fused
// epilogue: cols <2304 -> qkv fp32;  cols >=2304 -> silu -> bf16 A2[:,768..]
// 128x128 tile, BK=32, 4 waves, 4x4 16x16x32 mfma per wave
// ---------------------------------------------------------------------------
__global__ __launch_bounds__(256) void gemm1_kernel(
    const unsigned short* __restrict__ A,   // 1792 x 768
    const unsigned short* __restrict__ Bt,  // 5376 x 768
    const float* __restrict__ bias,
    float* __restrict__ qkv,                // 1728 x 2304
    unsigned short* __restrict__ A2)        // 1792 x 3840
{
    const int K = DIM_;
    __shared__ unsigned short As[128 * 32];
    __shared__ unsigned short Bs[128 * 32];
    int tid = threadIdx.x;
    int bm = blockIdx.y * 128;
    int bn = blockIdx.x * 128;
    int wave = tid >> 6, lane = tid & 63;
    int quad = lane >> 4, l16 = lane & 15;
    int wm = (wave & 1) * 64;
    int wn = (wave >> 1) * 64;
    f32x4 acc[4][4] = {};
    int srow = tid >> 2;                // 0..63
    int skk  = (tid & 3) * 8;
    const unsigned short* Ag = A + (size_t)(bm + srow) * K + skk;
    const unsigned short* Bg = Bt + (size_t)(bn + srow) * K + skk;
    unsigned short* la0 = &As[srow * 32 + skk];
    unsigned short* la1 = &As[(srow + 64) * 32 + skk];
    unsigned short* lb0 = &Bs[srow * 32 + skk];
    unsigned short* lb1 = &Bs[(srow + 64) * 32 + skk];
    for (int k0 = 0; k0 < K; k0 += 32) {
        async_copy16(Ag + k0, la0);
        async_copy16(Ag + (size_t)64 * K + k0, la1);
        async_copy16(Bg + k0, lb0);
        async_copy16(Bg + (size_t)64 * K + k0, lb1);
        __syncthreads();
        bf16x8 af[4], bf[4];
#pragma unroll
        for (int mt = 0; mt < 4; ++mt)
            af[mt] = *(const bf16x8*)&As[(wm + mt * 16 + l16) * 32 + quad * 8];
#pragma unroll
        for (int nt = 0; nt < 4; ++nt)
            bf[nt] = *(const bf16x8*)&Bs[(wn + nt * 16 + l16) * 32 + quad * 8];
#pragma unroll
        for (int mt = 0; mt < 4; ++mt)
#pragma unroll
            for (int nt = 0; nt < 4; ++nt)
                acc[mt][nt] = __builtin_amdgcn_mfma_f32_16x16x32_bf16(
                    af[mt], bf[nt], acc[mt][nt], 0, 0, 0);
        __syncthreads();
    }
    // epilogue: C/D layout col=lane&15, row=quad*4+reg
#pragma unroll
    for (int mt = 0; mt < 4; ++mt) {
#pragma unroll
        for (int nt = 0; nt < 4; ++nt) {
            int gcol = bn + wn + nt * 16 + l16;
            float b = bias[gcol];
#pragma unroll
            for (int r = 0; r < 4; ++r) {
                int grow = bm + wm + mt * 16 + quad * 4 + r;
                if (grow < THW_) {
                    float v = acc[mt][nt][r] + b;
                    if (gcol < QKV_)
                        qkv[(size_t)grow * QKV_ + gcol] = v;
                    else
                        A2[(size_t)grow * KTOT_ + (gcol - QKV_ + DIM_)] = f2bf(siluf(v));
                }
            }
        }
    }
}

// ---------------------------------------------------------------------------
// K4: per (head, token) wave: LN(q), LN(k) over DH=48, RoPE, q*=1/sqrt(48)
// ---------------------------------------------------------------------------
__global__ __launch_bounds__(256) void qkln_rope_kernel(
    const float* __restrict__ qkv,
    const float* __restrict__ qn_w, const float* __restrict__ qn_b,
    const float* __restrict__ kn_w, const float* __restrict__ kn_b,
    float* __restrict__ qb, float* __restrict__ kb)
{
    int tid = threadIdx.x;
    int lane = tid & 63, wid = tid >> 6;
    int idx = blockIdx.x * 4 + wid;
    int head = idx / THW_;
    int m = idx - head * THW_;
    const float* fp = qkv + (size_t)m * QKV_ + head * DH_;
    float qv = 0.f, kv = 0.f;
    if (lane < DH_) { qv = fp[lane]; kv = fp[768 + lane]; }
    float s = qv, sq = qv * qv, sk = kv, sqk = kv * kv;
#pragma unroll
    for (int off = 32; off > 0; off >>= 1) {
        s   += __shfl_xor(s, off, 64);
        sq  += __shfl_xor(sq, off, 64);
        sk  += __shfl_xor(sk, off, 64);
        sqk += __shfl_xor(sqk, off, 64);
    }
    float mq = s  * (1.f / 48.f), vq = sq  * (1.f / 48.f) - mq * mq;
    float mk = sk * (1.f / 48.f), vk = sqk * (1.f / 48.f) - mk * mk;
    float qn = 0.f, kn = 0.f;
    if (lane < DH_) {
        qn = (qv - mq) * rsqrtf(vq + EPS_) * qn_w[lane] + qn_b[lane];
        kn = (kv - mk) * rsqrtf(vk + EPS_) * kn_w[lane] + kn_b[lane];
    }
    int t = m / HW_; int hw = m - t * HW_;
    int hh = hw / RES_; int ww = hw - hh * RES_;
    int i = lane >> 1;
    int grp = i >> 3, j = i & 7;
    float pos = (grp == 0) ? (float)t : (grp == 1) ? (float)hh : (float)ww;
    float invf = powf(10000.f, -(float)j * (2.f / 16.f));
    float ang = pos * invf;
    float cs = cosf(ang), sn = sinf(ang);
    float qp = __shfl_xor(qn, 1, 64);
    float kp = __shfl_xor(kn, 1, 64);
    float qo, ko;
    if ((lane & 1) == 0) { qo = qn * cs - qp * sn; ko = kn * cs - kp * sn; }
    else                 { qo = qp * sn + qn * cs; ko = kp * sn + kn * cs; }
    if (lane < DH_) {
        size_t o = ((size_t)head * THW_ + m) * DH_ + lane;
        qb[o] = qo * 0.14433756729740643f;
        kb[o] = ko;
    }
}

// ---------------------------------------------------------------------------
// K5: neighborhood attention; writes xa as bf16 into A2[:, 0:768]
// ---------------------------------------------------------------------------
__global__ __launch_bounds__(256) void attn_kernel(
    const float* __restrict__ qb, const float* __restrict__ kb,
    const float* __restrict__ qkv, unsigned short* __restrict__ A2)
{
    int tid = threadIdx.x;
    int lane = tid & 63, wid = tid >> 6;
    int idx = blockIdx.x * 4 + wid;
    int head = idx / THW_;
    int m = idx - head * THW_;
    int t = m / HW_; int hw = m - t * HW_;
    int hh = hw / RES_; int ww = hw - hh * RES_;
    int hs = min(max(hh - 2, 0), RES_ - 5);
    int wstart = min(max(ww - 2, 0), RES_ - 5);
    (void)t;
    __shared__ float qs[4][48];
    __shared__ float ps[4][80];
    if (lane < 48) qs[wid][lane] = qb[((size_t)head * THW_ + m) * DH_ + lane];
    __syncthreads();
    float s0, s1 = -1e30f;
    {
        int jj = lane;
        int a = jj / 25, rem = jj - a * 25, c = rem / 5, e = rem - c * 5;
        int nm = a * HW_ + (hs + c) * RES_ + (wstart + e);
        const float* kp = kb + ((size_t)head * THW_ + nm) * DH_;
        float acc = 0.f;
#pragma unroll
        for (int d = 0; d < 48; ++d) acc += qs[wid][d] * kp[d];
        s0 = acc;
    }
    if (lane < 11) {
        int jj = lane + 64;
        int a = jj / 25, rem = jj - a * 25, c = rem / 5, e = rem - c * 5;
        int nm = a * HW_ + (hs + c) * RES_ + (wstart + e);
        const float* kp = kb + ((size_t)head * THW_ + nm) * DH_;
        float acc = 0.f;
#pragma unroll
        for (int d = 0; d < 48; ++d) acc += qs[wid][d] * kp[d];
        s1 = acc;
    }
    float mx = fmaxf(s0, s1);
#pragma unroll
    for (int off = 32; off > 0; off >>= 1) mx = fmaxf(mx, __shfl_xor(mx, off, 64));
    float p0 = expf(s0 - mx);
    float p1 = (lane < 11) ? expf(s1 - mx) : 0.f;
    float sum = p0 + p1;
#pragma unroll
    for (int off = 32; off > 0; off >>= 1) sum += __shfl_xor(sum, off, 64);
    float invs = 1.f / sum;
    ps[wid][lane] = p0 * invs;
    if (lane < 11) ps[wid][lane + 64] = p1 * invs;
    __syncthreads();
    if (lane < 48) {
        float acc = 0.f;
        const float* vbase = qkv + 1536 + head * DH_ + lane;
        int j = 0;
        for (int a = 0; a < 3; ++a)
            for (int c = 0; c < 5; ++c) {
                int rowbase = a * HW_ + (hs + c) * RES_ + wstart;
#pragma unroll
                for (int e = 0; e < 5; ++e) {
                    acc += ps[wid][j] * vbase[(size_t)(rowbase + e) * QKV_];
                    ++j;
                }
            }
        A2[(size_t)m * KTOT_ + head * DH_ + lane] = f2bf(acc);
    }
}

// ---------------------------------------------------------------------------
// K6a: out = x + b_mlp (in output layout) — accumulation base for gemm2
// ---------------------------------------------------------------------------
__global__ __launch_bounds__(256) void out_init_kernel(
    const float* __restrict__ x, const float* __restrict__ b_mlp,
    float* __restrict__ out)
{
    int i = blockIdx.x * 256 + threadIdx.x;     // < 1,327,104
    int c = (i / HW_) % DIM_;
    out[i] = x[i] + b_mlp[c];
}

// ---------------------------------------------------------------------------
// K6b: MFMA GEMM2 (split-K=6): out += A2(1792x3840) @ Bt2^T(768x3840)
// atomicAdd into out in (t, c, hw) layout
// ---------------------------------------------------------------------------
__global__ __launch_bounds__(256) void gemm2_kernel(
    const unsigned short* __restrict__ A,   // 1792 x 3840
    const unsigned short* __restrict__ Bt,  // 768 x 3840
    float* __restrict__ out)
{
    const int K = KTOT_;
    __shared__ unsigned short As[128 * 32];
    __shared__ unsigned short Bs[128 * 32];
    int tid = threadIdx.x;
    int bm = blockIdx.y * 128;
    int bn = blockIdx.x * 128;
    int ks = blockIdx.z * 640;
    int wave = tid >> 6, lane = tid & 63;
    int quad = lane >> 4, l16 = lane & 15;
    int wm = (wave & 1) * 64;
    int wn = (wave >> 1) * 64;
    f32x4 acc[4][4] = {};
    int srow = tid >> 2;
    int skk  = (tid & 3) * 8;
    const unsigned short* Ag = A + (size_t)(bm + srow) * K + skk;
    const unsigned short* Bg = Bt + (size_t)(bn + srow) * K + skk;
    unsigned short* la0 = &As[srow * 32 + skk];
    unsigned short* la1 = &As[(srow + 64) * 32 + skk];
    unsigned short* lb0 = &Bs[srow * 32 + skk];
    unsigned short* lb1 = &Bs[(srow + 64) * 32 + skk];
    for (int k0 = ks; k0 < ks + 640; k0 += 32) {
        async_copy16(Ag + k0, la0);
        async_copy16(Ag + (size_t)64 * K + k0, la1);
        async_copy16(Bg + k0, lb0);
        async_copy16(Bg + (size_t)64 * K + k0, lb1);
        __syncthreads();
        bf16x8 af[4], bf[4];
#pragma unroll
        for (int mt = 0; mt < 4; ++mt)
            af[mt] = *(const bf16x8*)&As[(wm + mt * 16 + l16) * 32 + quad * 8];
#pragma unroll
        for (int nt = 0; nt < 4; ++nt)
            bf[nt] = *(const bf16x8*)&Bs[(wn + nt * 16 + l16) * 32 + quad * 8];
#pragma unroll
        for (int mt = 0; mt < 4; ++mt)
#pragma unroll
            for (int nt = 0; nt < 4; ++nt)
                acc[mt][nt] = __builtin_amdgcn_mfma_f32_16x16x32_bf16(
                    af[mt], bf[nt], acc[mt][nt], 0, 0, 0);
        __syncthreads();
    }
#pragma unroll
    for (int mt = 0; mt < 4; ++mt) {
#pragma unroll
        for (int nt = 0; nt < 4; ++nt) {
            int gcol = bn + wn + nt * 16 + l16;
#pragma unroll
            for (int r = 0; r < 4; ++r) {
                int grow = bm + wm + mt * 16 + quad * 4 + r;
                if (grow < THW_) {
                    int t = grow / HW_, hw = grow - (grow / HW_) * HW_;
                    atomicAdd(out + ((size_t)t * DIM_ + gcol) * HW_ + hw,
                              acc[mt][nt][r]);
                }
            }
        }
    }
}

// ---------------------------------------------------------------------------
extern "C" void kernel_launch(void* const* d_in, const int* in_sizes, int n_in,
                              void* d_out, int out_size, void* d_ws, size_t ws_size,
                              hipStream_t stream) {
    const float* x       = (const float*)d_in[0];
    const float* emb     = (const float*)d_in[1];
    const float* w_mod   = (const float*)d_in[2];
    const float* b_mod   = (const float*)d_in[3];
    const float* qn_w    = (const float*)d_in[4];
    const float* qn_b    = (const float*)d_in[5];
    const float* kn_w    = (const float*)d_in[6];
    const float* kn_b    = (const float*)d_in[7];
    const float* W_fused = (const float*)d_in[8];
    const float* b_fused = (const float*)d_in[9];
    const float* W_out   = (const float*)d_in[10];
    const float* W_mlp   = (const float*)d_in[11];
    const float* b_mlp   = (const float*)d_in[12];
    float* out = (float*)d_out;

    char* w = (char*)d_ws;
    float* mod = (float*)w;            w += (size_t)4608 * 4;
    float* qkv = (float*)w;            w += (size_t)THW_ * QKV_ * 4;
    float* qb  = (float*)w;            w += (size_t)HEADS_ * THW_ * DH_ * 4;
    float* kb  = (float*)w;            w += (size_t)HEADS_ * THW_ * DH_ * 4;
    unsigned short* h   = (unsigned short*)w;  w += (size_t)MP_ * DIM_ * 2;
    unsigned short* A2  = (unsigned short*)w;  w += (size_t)MP_ * KTOT_ * 2;
    unsigned short* Bt1 = (unsigned short*)w;  w += (size_t)NF_ * DIM_ * 2;
    unsigned short* Bt2 = (unsigned short*)w;  w += (size_t)DIM_ * KTOT_ * 2;

    conv_wfused_kernel<<<dim3(NF_ / 32, DIM_ / 32), 256, 0, stream>>>(W_fused, Bt1);
    conv_wcat_kernel<<<dim3(KTOT_ / 32, DIM_ / 32), 256, 0, stream>>>(W_out, W_mlp, Bt2);
    mod_kernel<<<dim3(12, 3), 256, 0, stream>>>(emb, w_mod, b_mod, mod);
    ln_mod_kernel<<<THW_, 256, 0, stream>>>(x, mod, h);
    gemm1_kernel<<<dim3(NF_ / 128, MP_ / 128), 256, 0, stream>>>(h, Bt1, b_fused, qkv, A2);
    qkln_rope_kernel<<<(HEADS_ * THW_) / 4, 256, 0, stream>>>(qkv, qn_w, qn_b, kn_w, kn_b, qb, kb);
    attn_kernel<<<(HEADS_ * THW_) / 4, 256, 0, stream>>>(qb, kb, qkv, A2);
    out_init_kernel<<<(T_ * DIM_ * HW_) / 256, 256, 0, stream>>>(x, b_mlp, out);
    gemm2_kernel<<<dim3(DIM_ / 128, MP_ / 128, 6), 256, 0, stream>>>(A2, Bt2, out);
}

// Round 3
// 351.889 us; speedup vs baseline: 2.1931x; 1.0382x over previous
//
#include <hip/hip_runtime.h>
#include <hip/hip_bf16.h>
#include <math.h>

#define T_    3
#define RES_  24
#define DIM_  768
#define HEADS_ 16
#define DH_   48
#define EMB_  1024
#define HW_   576            // RES*RES
#define THW_  1728           // T*HW
#define MP_   1792           // THW padded to multiple of 128
#define MLP_  3072
#define NF_   5376           // 3*DIM + MLP
#define QKV_  2304           // 3*DIM
#define KTOT_ 3840           // DIM + MLP (second GEMM K)
#define SPLITK_ 6
#define EPS_  1e-5f

typedef __attribute__((ext_vector_type(8))) short bf16x8;
typedef __attribute__((ext_vector_type(4))) float f32x4;

__device__ __forceinline__ float siluf(float x) { return x / (1.f + expf(-x)); }

__device__ __forceinline__ unsigned short f2bf(float f) {
    __hip_bfloat16 b = __float2bfloat16(f);
    return *reinterpret_cast<unsigned short*>(&b);
}

__device__ __forceinline__ float bf2f(unsigned short u) {
    return __uint_as_float(((unsigned)u) << 16);
}

__device__ __forceinline__ void async_copy16(const void* g, void* l) {
    __builtin_amdgcn_global_load_lds(
        (__attribute__((address_space(1))) void*)g,
        (__attribute__((address_space(3))) void*)l,
        16, 0, 0);
}

// ---------------------------------------------------------------------------
// K0a: W_fused (768 x 5376 f32) -> Bt1 (5376 x 768 bf16)   [transposed]
// ---------------------------------------------------------------------------
__global__ __launch_bounds__(256) void conv_wfused_kernel(
    const float* __restrict__ W, unsigned short* __restrict__ Wt)
{
    __shared__ float tile[32][33];
    int n0 = blockIdx.x * 32;
    int k0 = blockIdx.y * 32;
    int c = threadIdx.x & 31;
    int r = threadIdx.x >> 5;
#pragma unroll
    for (int i = 0; i < 4; ++i)
        tile[r + 8 * i][c] = W[(size_t)(k0 + r + 8 * i) * NF_ + n0 + c];
    __syncthreads();
#pragma unroll
    for (int i = 0; i < 4; ++i)
        Wt[(size_t)(n0 + r + 8 * i) * DIM_ + k0 + c] = f2bf(tile[c][r + 8 * i]);
}

// ---------------------------------------------------------------------------
// K0b: [W_out;W_mlp] (3840 x 768 f32) -> Bt2 (768 x 3840 bf16)  [transposed]
// ---------------------------------------------------------------------------
__global__ __launch_bounds__(256) void conv_wcat_kernel(
    const float* __restrict__ W_out, const float* __restrict__ W_mlp,
    unsigned short* __restrict__ Wt)
{
    __shared__ float tile[32][33];
    int k0 = blockIdx.x * 32;
    int n0 = blockIdx.y * 32;
    int c = threadIdx.x & 31;
    int r = threadIdx.x >> 5;
#pragma unroll
    for (int i = 0; i < 4; ++i) {
        int k = k0 + r + 8 * i;
        float v = (k < DIM_) ? W_out[(size_t)k * DIM_ + n0 + c]
                             : W_mlp[(size_t)(k - DIM_) * DIM_ + n0 + c];
        tile[r + 8 * i][c] = v;
    }
    __syncthreads();
#pragma unroll
    for (int i = 0; i < 4; ++i)
        Wt[(size_t)(n0 + r + 8 * i) * KTOT_ + k0 + c] = f2bf(tile[c][r + 8 * i]);
}

// ---------------------------------------------------------------------------
// K1: mod[t][j] = silu(emb[t]) @ w_mod + b_mod   (3 x 1536)
// ---------------------------------------------------------------------------
__global__ __launch_bounds__(256) void mod_kernel(
    const float* __restrict__ emb, const float* __restrict__ w_mod,
    const float* __restrict__ b_mod, float* __restrict__ mod)
{
    int t = blockIdx.y;
    int chunk = blockIdx.x;
    __shared__ float se[EMB_];
    __shared__ float part[128];
    int tid = threadIdx.x;
    for (int i = tid; i < EMB_; i += 256) {
        float e = emb[t * EMB_ + i];
        se[i] = e / (1.f + expf(-e));
    }
    __syncthreads();
    int r = tid >> 7;
    int c = tid & 127;
    int j = chunk * 128 + c;
    const float* wp = w_mod + j;
    float acc = 0.f;
    for (int e = r * 512; e < r * 512 + 512; ++e)
        acc += se[e] * wp[e * 1536];
    if (r == 1) part[c] = acc;
    __syncthreads();
    if (r == 0)
        mod[t * 1536 + j] = acc + part[c] + b_mod[j];
}

// ---------------------------------------------------------------------------
// K2: h[m][c] = bf16( LN(x[t,:,hw])[c] * (1+scale[t,c]) + shift[t,c] )
// ---------------------------------------------------------------------------
__global__ __launch_bounds__(256) void ln_mod_kernel(
    const float* __restrict__ x, const float* __restrict__ mod,
    unsigned short* __restrict__ h)
{
    int m = blockIdx.x;
    int t = m / HW_;
    int hw = m - t * HW_;
    const float* xp = x + (size_t)t * DIM_ * HW_ + hw;
    int tid = threadIdx.x;
    float v0 = xp[(size_t)tid * HW_];
    float v1 = xp[(size_t)(tid + 256) * HW_];
    float v2 = xp[(size_t)(tid + 512) * HW_];
    float s  = v0 + v1 + v2;
    float sq = v0 * v0 + v1 * v1 + v2 * v2;
#pragma unroll
    for (int off = 32; off > 0; off >>= 1) {
        s  += __shfl_xor(s, off, 64);
        sq += __shfl_xor(sq, off, 64);
    }
    __shared__ float ssum[4], ssq[4];
    int lane = tid & 63, wid = tid >> 6;
    if (lane == 0) { ssum[wid] = s; ssq[wid] = sq; }
    __syncthreads();
    float tot  = ssum[0] + ssum[1] + ssum[2] + ssum[3];
    float totq = ssq[0] + ssq[1] + ssq[2] + ssq[3];
    float mean = tot * (1.f / 768.f);
    float var  = totq * (1.f / 768.f) - mean * mean;
    float rs = rsqrtf(var + EPS_);
    const float* sc = mod + t * 1536;
    const float* sh = sc + 768;
    unsigned short* hp = h + (size_t)m * DIM_;
    hp[tid]       = f2bf((v0 - mean) * rs * (1.f + sc[tid])       + sh[tid]);
    hp[tid + 256] = f2bf((v1 - mean) * rs * (1.f + sc[tid + 256]) + sh[tid + 256]);
    hp[tid + 512] = f2bf((v2 - mean) * rs * (1.f + sc[tid + 512]) + sh[tid + 512]);
}

// ---------------------------------------------------------------------------
// K3: MFMA GEMM1: C = h(1792x768) @ Bt1^T(5376x768) + b_fused
// epilogue: cols <2304 -> qkv fp32;  cols >=2304 -> silu -> bf16 A2[:,768..]
// ---------------------------------------------------------------------------
__global__ __launch_bounds__(256) void gemm1_kernel(
    const unsigned short* __restrict__ A,   // 1792 x 768
    const unsigned short* __restrict__ Bt,  // 5376 x 768
    const float* __restrict__ bias,
    float* __restrict__ qkv,                // 1728 x 2304
    unsigned short* __restrict__ A2)        // 1792 x 3840
{
    const int K = DIM_;
    __shared__ unsigned short As[128 * 32];
    __shared__ unsigned short Bs[128 * 32];
    int tid = threadIdx.x;
    int bm = blockIdx.y * 128;
    int bn = blockIdx.x * 128;
    int wave = tid >> 6, lane = tid & 63;
    int quad = lane >> 4, l16 = lane & 15;
    int wm = (wave & 1) * 64;
    int wn = (wave >> 1) * 64;
    f32x4 acc[4][4] = {};
    int srow = tid >> 2;
    int skk  = (tid & 3) * 8;
    const unsigned short* Ag = A + (size_t)(bm + srow) * K + skk;
    const unsigned short* Bg = Bt + (size_t)(bn + srow) * K + skk;
    unsigned short* la0 = &As[srow * 32 + skk];
    unsigned short* la1 = &As[(srow + 64) * 32 + skk];
    unsigned short* lb0 = &Bs[srow * 32 + skk];
    unsigned short* lb1 = &Bs[(srow + 64) * 32 + skk];
    for (int k0 = 0; k0 < K; k0 += 32) {
        async_copy16(Ag + k0, la0);
        async_copy16(Ag + (size_t)64 * K + k0, la1);
        async_copy16(Bg + k0, lb0);
        async_copy16(Bg + (size_t)64 * K + k0, lb1);
        __syncthreads();
        bf16x8 af[4], bf[4];
#pragma unroll
        for (int mt = 0; mt < 4; ++mt)
            af[mt] = *(const bf16x8*)&As[(wm + mt * 16 + l16) * 32 + quad * 8];
#pragma unroll
        for (int nt = 0; nt < 4; ++nt)
            bf[nt] = *(const bf16x8*)&Bs[(wn + nt * 16 + l16) * 32 + quad * 8];
#pragma unroll
        for (int mt = 0; mt < 4; ++mt)
#pragma unroll
            for (int nt = 0; nt < 4; ++nt)
                acc[mt][nt] = __builtin_amdgcn_mfma_f32_16x16x32_bf16(
                    af[mt], bf[nt], acc[mt][nt], 0, 0, 0);
        __syncthreads();
    }
#pragma unroll
    for (int mt = 0; mt < 4; ++mt) {
#pragma unroll
        for (int nt = 0; nt < 4; ++nt) {
            int gcol = bn + wn + nt * 16 + l16;
            float b = bias[gcol];
#pragma unroll
            for (int r = 0; r < 4; ++r) {
                int grow = bm + wm + mt * 16 + quad * 4 + r;
                if (grow < THW_) {
                    float v = acc[mt][nt][r] + b;
                    if (gcol < QKV_)
                        qkv[(size_t)grow * QKV_ + gcol] = v;
                    else
                        A2[(size_t)grow * KTOT_ + (gcol - QKV_ + DIM_)] = f2bf(siluf(v));
                }
            }
        }
    }
}

// ---------------------------------------------------------------------------
// K4: per (head, token) wave: LN(q), LN(k) over DH=48, RoPE, q*=1/sqrt(48)
// ---------------------------------------------------------------------------
__global__ __launch_bounds__(256) void qkln_rope_kernel(
    const float* __restrict__ qkv,
    const float* __restrict__ qn_w, const float* __restrict__ qn_b,
    const float* __restrict__ kn_w, const float* __restrict__ kn_b,
    float* __restrict__ qb, float* __restrict__ kb)
{
    int tid = threadIdx.x;
    int lane = tid & 63, wid = tid >> 6;
    int idx = blockIdx.x * 4 + wid;
    int head = idx / THW_;
    int m = idx - head * THW_;
    const float* fp = qkv + (size_t)m * QKV_ + head * DH_;
    float qv = 0.f, kv = 0.f;
    if (lane < DH_) { qv = fp[lane]; kv = fp[768 + lane]; }
    float s = qv, sq = qv * qv, sk = kv, sqk = kv * kv;
#pragma unroll
    for (int off = 32; off > 0; off >>= 1) {
        s   += __shfl_xor(s, off, 64);
        sq  += __shfl_xor(sq, off, 64);
        sk  += __shfl_xor(sk, off, 64);
        sqk += __shfl_xor(sqk, off, 64);
    }
    float mq = s  * (1.f / 48.f), vq = sq  * (1.f / 48.f) - mq * mq;
    float mk = sk * (1.f / 48.f), vk = sqk * (1.f / 48.f) - mk * mk;
    float qn = 0.f, kn = 0.f;
    if (lane < DH_) {
        qn = (qv - mq) * rsqrtf(vq + EPS_) * qn_w[lane] + qn_b[lane];
        kn = (kv - mk) * rsqrtf(vk + EPS_) * kn_w[lane] + kn_b[lane];
    }
    int t = m / HW_; int hw = m - t * HW_;
    int hh = hw / RES_; int ww = hw - hh * RES_;
    int i = lane >> 1;
    int grp = i >> 3, j = i & 7;
    float pos = (grp == 0) ? (float)t : (grp == 1) ? (float)hh : (float)ww;
    float invf = exp2f(-1.6609640474436813f * (float)j);   // 10000^(-j/8)
    float ang = pos * invf;
    float cs = cosf(ang), sn = sinf(ang);
    float qp = __shfl_xor(qn, 1, 64);
    float kp = __shfl_xor(kn, 1, 64);
    float qo, ko;
    if ((lane & 1) == 0) { qo = qn * cs - qp * sn; ko = kn * cs - kp * sn; }
    else                 { qo = qp * sn + qn * cs; ko = kp * sn + kn * cs; }
    if (lane < DH_) {
        size_t o = ((size_t)head * THW_ + m) * DH_ + lane;
        qb[o] = qo * 0.14433756729740643f;
        kb[o] = ko;
    }
}

// ---------------------------------------------------------------------------
// K5: neighborhood attention, 2 waves/block, one (head,token) per wave.
// K rows staged cooperatively into LDS (stride 49 -> 2-way bank alias, free);
// score dot runs from LDS instead of a 64-line global gather.
// ---------------------------------------------------------------------------
__global__ __launch_bounds__(128) void attn_kernel(
    const float* __restrict__ qb, const float* __restrict__ kb,
    const float* __restrict__ qkv, unsigned short* __restrict__ A2)
{
    __shared__ float Ks[2][75 * 49];
    __shared__ float qs[2][48];
    __shared__ float ps[2][80];
    int tid = threadIdx.x;
    int lane = tid & 63, wid = tid >> 6;
    int idx = blockIdx.x * 2 + wid;
    int head = idx / THW_;
    int m = idx - head * THW_;
    int t = m / HW_; int hw = m - t * HW_;
    int hh = hw / RES_; int ww = hw - hh * RES_;
    int hs = min(max(hh - 2, 0), RES_ - 5);
    int wstart = min(max(ww - 2, 0), RES_ - 5);
    (void)t;
    const float* kbh = kb + (size_t)head * THW_ * DH_;
    float* ks = Ks[wid];
    // cooperative K staging: 75 rows x 48 floats, coalesced along d
    for (int i = lane; i < 75 * 48; i += 64) {
        int r = (int)((unsigned)i / 48u);
        int d = i - r * 48;
        int a = (int)((unsigned)r / 25u);
        int rem = r - a * 25;
        int c = (int)((unsigned)rem / 5u);
        int e = rem - c * 5;
        int nm = a * HW_ + (hs + c) * RES_ + (wstart + e);
        ks[r * 49 + d] = kbh[(size_t)nm * DH_ + d];
    }
    if (lane < 48) qs[wid][lane] = qb[((size_t)head * THW_ + m) * DH_ + lane];
    __syncthreads();
    // scores from LDS
    float s0, s1 = -1e30f;
    {
        const float* kr = ks + lane * 49;
        float acc = 0.f;
#pragma unroll
        for (int d = 0; d < 48; ++d) acc += qs[wid][d] * kr[d];
        s0 = acc;
    }
    if (lane < 11) {
        const float* kr = ks + (lane + 64) * 49;
        float acc = 0.f;
#pragma unroll
        for (int d = 0; d < 48; ++d) acc += qs[wid][d] * kr[d];
        s1 = acc;
    }
    float mx = fmaxf(s0, s1);
#pragma unroll
    for (int off = 32; off > 0; off >>= 1) mx = fmaxf(mx, __shfl_xor(mx, off, 64));
    float p0 = expf(s0 - mx);
    float p1 = (lane < 11) ? expf(s1 - mx) : 0.f;
    float sum = p0 + p1;
#pragma unroll
    for (int off = 32; off > 0; off >>= 1) sum += __shfl_xor(sum, off, 64);
    float invs = 1.f / sum;
    ps[wid][lane] = p0 * invs;
    if (lane < 11) ps[wid][lane + 64] = p1 * invs;
    __syncthreads();
    // P.V: lanes vary along d (coalesced 192B row reads from qkv)
    if (lane < 48) {
        float acc = 0.f;
        const float* vbase = qkv + 1536 + head * DH_ + lane;
        int j = 0;
        for (int a = 0; a < 3; ++a)
            for (int c = 0; c < 5; ++c) {
                int rowbase = a * HW_ + (hs + c) * RES_ + wstart;
#pragma unroll
                for (int e = 0; e < 5; ++e) {
                    acc += ps[wid][j] * vbase[(size_t)(rowbase + e) * QKV_];
                    ++j;
                }
            }
        A2[(size_t)m * KTOT_ + head * DH_ + lane] = f2bf(acc);
    }
}

// ---------------------------------------------------------------------------
// K6: MFMA GEMM2 (split-K=6): P[s] = A2(1792x3840) @ Bt2^T(768x3840), slice s
// plain coalesced bf16 stores, NO atomics
// ---------------------------------------------------------------------------
__global__ __launch_bounds__(256) void gemm2_kernel(
    const unsigned short* __restrict__ A,   // 1792 x 3840
    const unsigned short* __restrict__ Bt,  // 768 x 3840
    unsigned short* __restrict__ P)         // 6 x 1792 x 768
{
    const int K = KTOT_;
    __shared__ unsigned short As[128 * 32];
    __shared__ unsigned short Bs[128 * 32];
    int tid = threadIdx.x;
    int bm = blockIdx.y * 128;
    int bn = blockIdx.x * 128;
    int ks = blockIdx.z * (KTOT_ / SPLITK_);
    int wave = tid >> 6, lane = tid & 63;
    int quad = lane >> 4, l16 = lane & 15;
    int wm = (wave & 1) * 64;
    int wn = (wave >> 1) * 64;
    f32x4 acc[4][4] = {};
    int srow = tid >> 2;
    int skk  = (tid & 3) * 8;
    const unsigned short* Ag = A + (size_t)(bm + srow) * K + skk;
    const unsigned short* Bg = Bt + (size_t)(bn + srow) * K + skk;
    unsigned short* la0 = &As[srow * 32 + skk];
    unsigned short* la1 = &As[(srow + 64) * 32 + skk];
    unsigned short* lb0 = &Bs[srow * 32 + skk];
    unsigned short* lb1 = &Bs[(srow + 64) * 32 + skk];
    for (int k0 = ks; k0 < ks + KTOT_ / SPLITK_; k0 += 32) {
        async_copy16(Ag + k0, la0);
        async_copy16(Ag + (size_t)64 * K + k0, la1);
        async_copy16(Bg + k0, lb0);
        async_copy16(Bg + (size_t)64 * K + k0, lb1);
        __syncthreads();
        bf16x8 af[4], bf[4];
#pragma unroll
        for (int mt = 0; mt < 4; ++mt)
            af[mt] = *(const bf16x8*)&As[(wm + mt * 16 + l16) * 32 + quad * 8];
#pragma unroll
        for (int nt = 0; nt < 4; ++nt)
            bf[nt] = *(const bf16x8*)&Bs[(wn + nt * 16 + l16) * 32 + quad * 8];
#pragma unroll
        for (int mt = 0; mt < 4; ++mt)
#pragma unroll
            for (int nt = 0; nt < 4; ++nt)
                acc[mt][nt] = __builtin_amdgcn_mfma_f32_16x16x32_bf16(
                    af[mt], bf[nt], acc[mt][nt], 0, 0, 0);
        __syncthreads();
    }
    unsigned short* Pp = P + (size_t)blockIdx.z * MP_ * DIM_;
#pragma unroll
    for (int mt = 0; mt < 4; ++mt) {
#pragma unroll
        for (int nt = 0; nt < 4; ++nt) {
            int gcol = bn + wn + nt * 16 + l16;
#pragma unroll
            for (int r = 0; r < 4; ++r) {
                int grow = bm + wm + mt * 16 + quad * 4 + r;
                if (grow < THW_)
                    Pp[(size_t)grow * DIM_ + gcol] = f2bf(acc[mt][nt][r]);
            }
        }
    }
}

// ---------------------------------------------------------------------------
// K7: out[(t*DIM+n)*HW+hw] = x + b_mlp[n] + sum_s P[s][m][n]
// tile 64m x 32n; LDS transpose; coalesced on both sides (576 = 9*64 so a
// 64-m run never crosses a t boundary)
// ---------------------------------------------------------------------------
__global__ __launch_bounds__(256) void reduce_out_kernel(
    const unsigned short* __restrict__ P, const float* __restrict__ x,
    const float* __restrict__ b_mlp, float* __restrict__ out)
{
    __shared__ float tile[32][65];
    int bm = blockIdx.x * 64;
    int bn = blockIdx.y * 32;
    int tid = threadIdx.x;
    int t = bm / HW_;
    int hw0 = bm - t * HW_;
    // phase A: read partials (n-contiguous ushort4), sum, store transposed
    for (int i = tid; i < 512; i += 256) {
        int ml = i >> 3;            // 0..63
        int n4 = (i & 7) * 4;       // 0,4,..,28
        float s0 = 0.f, s1 = 0.f, s2 = 0.f, s3 = 0.f;
#pragma unroll
        for (int sI = 0; sI < SPLITK_; ++sI) {
            const unsigned short* pp =
                P + ((size_t)sI * MP_ + bm + ml) * DIM_ + bn + n4;
            ushort4 u = *(const ushort4*)pp;
            s0 += bf2f(u.x); s1 += bf2f(u.y);
            s2 += bf2f(u.z); s3 += bf2f(u.w);
        }
        tile[n4 + 0][ml] = s0;
        tile[n4 + 1][ml] = s1;
        tile[n4 + 2][ml] = s2;
        tile[n4 + 3][ml] = s3;
    }
    __syncthreads();
    // phase B: write out coalesced along hw
    for (int i = tid; i < 512; i += 256) {
        int n = i >> 4;             // 0..31
        int ms = (i & 15) * 4;      // 0,4,..,60
        int gn = bn + n;
        size_t base = ((size_t)t * DIM_ + gn) * HW_ + hw0 + ms;
        float bv = b_mlp[gn];
        float4 xv = *(const float4*)(x + base);
        float4 o;
        o.x = xv.x + bv + tile[n][ms + 0];
        o.y = xv.y + bv + tile[n][ms + 1];
        o.z = xv.z + bv + tile[n][ms + 2];
        o.w = xv.w + bv + tile[n][ms + 3];
        *(float4*)(out + base) = o;
    }
}

// ---------------------------------------------------------------------------
extern "C" void kernel_launch(void* const* d_in, const int* in_sizes, int n_in,
                              void* d_out, int out_size, void* d_ws, size_t ws_size,
                              hipStream_t stream) {
    const float* x       = (const float*)d_in[0];
    const float* emb     = (const float*)d_in[1];
    const float* w_mod   = (const float*)d_in[2];
    const float* b_mod   = (const float*)d_in[3];
    const float* qn_w    = (const float*)d_in[4];
    const float* qn_b    = (const float*)d_in[5];
    const float* kn_w    = (const float*)d_in[6];
    const float* kn_b    = (const float*)d_in[7];
    const float* W_fused = (const float*)d_in[8];
    const float* b_fused = (const float*)d_in[9];
    const float* W_out   = (const float*)d_in[10];
    const float* W_mlp   = (const float*)d_in[11];
    const float* b_mlp   = (const float*)d_in[12];
    float* out = (float*)d_out;

    char* w = (char*)d_ws;
    float* mod = (float*)w;            w += (size_t)4608 * 4;
    float* qkv = (float*)w;            w += (size_t)THW_ * QKV_ * 4;
    float* qb  = (float*)w;            w += (size_t)HEADS_ * THW_ * DH_ * 4;
    float* kb  = (float*)w;            w += (size_t)HEADS_ * THW_ * DH_ * 4;
    unsigned short* h   = (unsigned short*)w;  w += (size_t)MP_ * DIM_ * 2;
    unsigned short* A2  = (unsigned short*)w;  w += (size_t)MP_ * KTOT_ * 2;
    unsigned short* Bt1 = (unsigned short*)w;  w += (size_t)NF_ * DIM_ * 2;
    unsigned short* Bt2 = (unsigned short*)w;  w += (size_t)DIM_ * KTOT_ * 2;
    unsigned short* P   = (unsigned short*)w;  w += (size_t)SPLITK_ * MP_ * DIM_ * 2;

    conv_wfused_kernel<<<dim3(NF_ / 32, DIM_ / 32), 256, 0, stream>>>(W_fused, Bt1);
    conv_wcat_kernel<<<dim3(KTOT_ / 32, DIM_ / 32), 256, 0, stream>>>(W_out, W_mlp, Bt2);
    mod_kernel<<<dim3(12, 3), 256, 0, stream>>>(emb, w_mod, b_mod, mod);
    ln_mod_kernel<<<THW_, 256, 0, stream>>>(x, mod, h);
    gemm1_kernel<<<dim3(NF_ / 128, MP_ / 128), 256, 0, stream>>>(h, Bt1, b_fused, qkv, A2);
    qkln_rope_kernel<<<(HEADS_ * THW_) / 4, 256, 0, stream>>>(qkv, qn_w, qn_b, kn_w, kn_b, qb, kb);
    attn_kernel<<<(HEADS_ * THW_) / 2, 128, 0, stream>>>(qb, kb, qkv, A2);
    gemm2_kernel<<<dim3(DIM_ / 128, MP_ / 128, SPLITK_), 256, 0, stream>>>(A2, Bt2, P);
    reduce_out_kernel<<<dim3(THW_ / 64, DIM_ / 32), 256, 0, stream>>>(P, x, b_mlp, out);
}

// Round 4
// 247.597 us; speedup vs baseline: 3.1169x; 1.4212x over previous
//
#include <hip/hip_runtime.h>
#include <hip/hip_bf16.h>
#include <math.h>

#define T_    3
#define RES_  24
#define DIM_  768
#define HEADS_ 16
#define DH_   48
#define EMB_  1024
#define HW_   576            // RES*RES
#define THW_  1728           // T*HW
#define MP_   1792           // THW padded to multiple of 128
#define MLP_  3072
#define NF_   5376           // 3*DIM + MLP
#define QKV_  2304           // 3*DIM
#define KTOT_ 3840           // DIM + MLP (second GEMM K)
#define SPLITK_ 6
#define EPS_  1e-5f

typedef __attribute__((ext_vector_type(8))) short bf16x8;
typedef __attribute__((ext_vector_type(4))) float f32x4;

__device__ __forceinline__ float siluf(float x) { return x / (1.f + expf(-x)); }

__device__ __forceinline__ unsigned short f2bf(float f) {
    __hip_bfloat16 b = __float2bfloat16(f);
    return *reinterpret_cast<unsigned short*>(&b);
}

__device__ __forceinline__ float bf2f(unsigned short u) {
    return __uint_as_float(((unsigned)u) << 16);
}

__device__ __forceinline__ void async_copy16(const void* g, void* l) {
    __builtin_amdgcn_global_load_lds(
        (__attribute__((address_space(1))) void*)g,
        (__attribute__((address_space(3))) void*)l,
        16, 0, 0);
}

// ---------------------------------------------------------------------------
// K0a: W_fused (768 x 5376 f32) -> Bt1 (5376 x 768 bf16)   [transposed]
// ---------------------------------------------------------------------------
__global__ __launch_bounds__(256) void conv_wfused_kernel(
    const float* __restrict__ W, unsigned short* __restrict__ Wt)
{
    __shared__ float tile[32][33];
    int n0 = blockIdx.x * 32;
    int k0 = blockIdx.y * 32;
    int c = threadIdx.x & 31;
    int r = threadIdx.x >> 5;
#pragma unroll
    for (int i = 0; i < 4; ++i)
        tile[r + 8 * i][c] = W[(size_t)(k0 + r + 8 * i) * NF_ + n0 + c];
    __syncthreads();
#pragma unroll
    for (int i = 0; i < 4; ++i)
        Wt[(size_t)(n0 + r + 8 * i) * DIM_ + k0 + c] = f2bf(tile[c][r + 8 * i]);
}

// ---------------------------------------------------------------------------
// K0b: [W_out;W_mlp] (3840 x 768 f32) -> Bt2 (768 x 3840 bf16)  [transposed]
// ---------------------------------------------------------------------------
__global__ __launch_bounds__(256) void conv_wcat_kernel(
    const float* __restrict__ W_out, const float* __restrict__ W_mlp,
    unsigned short* __restrict__ Wt)
{
    __shared__ float tile[32][33];
    int k0 = blockIdx.x * 32;
    int n0 = blockIdx.y * 32;
    int c = threadIdx.x & 31;
    int r = threadIdx.x >> 5;
#pragma unroll
    for (int i = 0; i < 4; ++i) {
        int k = k0 + r + 8 * i;
        float v = (k < DIM_) ? W_out[(size_t)k * DIM_ + n0 + c]
                             : W_mlp[(size_t)(k - DIM_) * DIM_ + n0 + c];
        tile[r + 8 * i][c] = v;
    }
    __syncthreads();
#pragma unroll
    for (int i = 0; i < 4; ++i)
        Wt[(size_t)(n0 + r + 8 * i) * KTOT_ + k0 + c] = f2bf(tile[c][r + 8 * i]);
}

// ---------------------------------------------------------------------------
// K1: mod[t][j] = silu(emb[t]) @ w_mod + b_mod   (3 x 1536)
// ---------------------------------------------------------------------------
__global__ __launch_bounds__(256) void mod_kernel(
    const float* __restrict__ emb, const float* __restrict__ w_mod,
    const float* __restrict__ b_mod, float* __restrict__ mod)
{
    int t = blockIdx.y;
    int chunk = blockIdx.x;
    __shared__ float se[EMB_];
    __shared__ float part[128];
    int tid = threadIdx.x;
    for (int i = tid; i < EMB_; i += 256) {
        float e = emb[t * EMB_ + i];
        se[i] = e / (1.f + expf(-e));
    }
    __syncthreads();
    int r = tid >> 7;
    int c = tid & 127;
    int j = chunk * 128 + c;
    const float* wp = w_mod + j;
    float acc = 0.f;
    for (int e = r * 512; e < r * 512 + 512; ++e)
        acc += se[e] * wp[e * 1536];
    if (r == 1) part[c] = acc;
    __syncthreads();
    if (r == 0)
        mod[t * 1536 + j] = acc + part[c] + b_mod[j];
}

// ---------------------------------------------------------------------------
// K2: h[m][c] = bf16( LN(x[t,:,hw])[c] * (1+scale[t,c]) + shift[t,c] )
// ---------------------------------------------------------------------------
__global__ __launch_bounds__(256) void ln_mod_kernel(
    const float* __restrict__ x, const float* __restrict__ mod,
    unsigned short* __restrict__ h)
{
    int m = blockIdx.x;
    int t = m / HW_;
    int hw = m - t * HW_;
    const float* xp = x + (size_t)t * DIM_ * HW_ + hw;
    int tid = threadIdx.x;
    float v0 = xp[(size_t)tid * HW_];
    float v1 = xp[(size_t)(tid + 256) * HW_];
    float v2 = xp[(size_t)(tid + 512) * HW_];
    float s  = v0 + v1 + v2;
    float sq = v0 * v0 + v1 * v1 + v2 * v2;
#pragma unroll
    for (int off = 32; off > 0; off >>= 1) {
        s  += __shfl_xor(s, off, 64);
        sq += __shfl_xor(sq, off, 64);
    }
    __shared__ float ssum[4], ssq[4];
    int lane = tid & 63, wid = tid >> 6;
    if (lane == 0) { ssum[wid] = s; ssq[wid] = sq; }
    __syncthreads();
    float tot  = ssum[0] + ssum[1] + ssum[2] + ssum[3];
    float totq = ssq[0] + ssq[1] + ssq[2] + ssq[3];
    float mean = tot * (1.f / 768.f);
    float var  = totq * (1.f / 768.f) - mean * mean;
    float rs = rsqrtf(var + EPS_);
    const float* sc = mod + t * 1536;
    const float* sh = sc + 768;
    unsigned short* hp = h + (size_t)m * DIM_;
    hp[tid]       = f2bf((v0 - mean) * rs * (1.f + sc[tid])       + sh[tid]);
    hp[tid + 256] = f2bf((v1 - mean) * rs * (1.f + sc[tid + 256]) + sh[tid + 256]);
    hp[tid + 512] = f2bf((v2 - mean) * rs * (1.f + sc[tid + 512]) + sh[tid + 512]);
}

// ---------------------------------------------------------------------------
// K3: MFMA GEMM1: C = h(1792x768) @ Bt1^T(5376x768) + b_fused
// ---------------------------------------------------------------------------
__global__ __launch_bounds__(256) void gemm1_kernel(
    const unsigned short* __restrict__ A,   // 1792 x 768
    const unsigned short* __restrict__ Bt,  // 5376 x 768
    const float* __restrict__ bias,
    float* __restrict__ qkv,                // 1728 x 2304
    unsigned short* __restrict__ A2)        // 1792 x 3840
{
    const int K = DIM_;
    __shared__ unsigned short As[128 * 32];
    __shared__ unsigned short Bs[128 * 32];
    int tid = threadIdx.x;
    int bm = blockIdx.y * 128;
    int bn = blockIdx.x * 128;
    int wave = tid >> 6, lane = tid & 63;
    int quad = lane >> 4, l16 = lane & 15;
    int wm = (wave & 1) * 64;
    int wn = (wave >> 1) * 64;
    f32x4 acc[4][4] = {};
    int srow = tid >> 2;
    int skk  = (tid & 3) * 8;
    const unsigned short* Ag = A + (size_t)(bm + srow) * K + skk;
    const unsigned short* Bg = Bt + (size_t)(bn + srow) * K + skk;
    unsigned short* la0 = &As[srow * 32 + skk];
    unsigned short* la1 = &As[(srow + 64) * 32 + skk];
    unsigned short* lb0 = &Bs[srow * 32 + skk];
    unsigned short* lb1 = &Bs[(srow + 64) * 32 + skk];
    for (int k0 = 0; k0 < K; k0 += 32) {
        async_copy16(Ag + k0, la0);
        async_copy16(Ag + (size_t)64 * K + k0, la1);
        async_copy16(Bg + k0, lb0);
        async_copy16(Bg + (size_t)64 * K + k0, lb1);
        __syncthreads();
        bf16x8 af[4], bf[4];
#pragma unroll
        for (int mt = 0; mt < 4; ++mt)
            af[mt] = *(const bf16x8*)&As[(wm + mt * 16 + l16) * 32 + quad * 8];
#pragma unroll
        for (int nt = 0; nt < 4; ++nt)
            bf[nt] = *(const bf16x8*)&Bs[(wn + nt * 16 + l16) * 32 + quad * 8];
#pragma unroll
        for (int mt = 0; mt < 4; ++mt)
#pragma unroll
            for (int nt = 0; nt < 4; ++nt)
                acc[mt][nt] = __builtin_amdgcn_mfma_f32_16x16x32_bf16(
                    af[mt], bf[nt], acc[mt][nt], 0, 0, 0);
        __syncthreads();
    }
#pragma unroll
    for (int mt = 0; mt < 4; ++mt) {
#pragma unroll
        for (int nt = 0; nt < 4; ++nt) {
            int gcol = bn + wn + nt * 16 + l16;
            float b = bias[gcol];
#pragma unroll
            for (int r = 0; r < 4; ++r) {
                int grow = bm + wm + mt * 16 + quad * 4 + r;
                if (grow < THW_) {
                    float v = acc[mt][nt][r] + b;
                    if (gcol < QKV_)
                        qkv[(size_t)grow * QKV_ + gcol] = v;
                    else
                        A2[(size_t)grow * KTOT_ + (gcol - QKV_ + DIM_)] = f2bf(siluf(v));
                }
            }
        }
    }
}

// ---------------------------------------------------------------------------
// K4: per (head, token) wave: LN(q), LN(k) over DH=48, RoPE, q*=1/sqrt(48)
// ---------------------------------------------------------------------------
__global__ __launch_bounds__(256) void qkln_rope_kernel(
    const float* __restrict__ qkv,
    const float* __restrict__ qn_w, const float* __restrict__ qn_b,
    const float* __restrict__ kn_w, const float* __restrict__ kn_b,
    float* __restrict__ qb, float* __restrict__ kb)
{
    int tid = threadIdx.x;
    int lane = tid & 63, wid = tid >> 6;
    int idx = blockIdx.x * 4 + wid;
    int head = idx / THW_;
    int m = idx - head * THW_;
    const float* fp = qkv + (size_t)m * QKV_ + head * DH_;
    float qv = 0.f, kv = 0.f;
    if (lane < DH_) { qv = fp[lane]; kv = fp[768 + lane]; }
    float s = qv, sq = qv * qv, sk = kv, sqk = kv * kv;
#pragma unroll
    for (int off = 32; off > 0; off >>= 1) {
        s   += __shfl_xor(s, off, 64);
        sq  += __shfl_xor(sq, off, 64);
        sk  += __shfl_xor(sk, off, 64);
        sqk += __shfl_xor(sqk, off, 64);
    }
    float mq = s  * (1.f / 48.f), vq = sq  * (1.f / 48.f) - mq * mq;
    float mk = sk * (1.f / 48.f), vk = sqk * (1.f / 48.f) - mk * mk;
    float qn = 0.f, kn = 0.f;
    if (lane < DH_) {
        qn = (qv - mq) * rsqrtf(vq + EPS_) * qn_w[lane] + qn_b[lane];
        kn = (kv - mk) * rsqrtf(vk + EPS_) * kn_w[lane] + kn_b[lane];
    }
    int t = m / HW_; int hw = m - t * HW_;
    int hh = hw / RES_; int ww = hw - hh * RES_;
    int i = lane >> 1;
    int grp = i >> 3, j = i & 7;
    float pos = (grp == 0) ? (float)t : (grp == 1) ? (float)hh : (float)ww;
    float invf = exp2f(-1.6609640474436813f * (float)j);   // 10000^(-j/8)
    float ang = pos * invf;
    float cs = cosf(ang), sn = sinf(ang);
    float qp = __shfl_xor(qn, 1, 64);
    float kp = __shfl_xor(kn, 1, 64);
    float qo, ko;
    if ((lane & 1) == 0) { qo = qn * cs - qp * sn; ko = kn * cs - kp * sn; }
    else                 { qo = qp * sn + qn * cs; ko = kp * sn + kn * cs; }
    if (lane < DH_) {
        size_t o = ((size_t)head * THW_ + m) * DH_ + lane;
        qb[o] = qo * 0.14433756729740643f;
        kb[o] = ko;
    }
}

// ---------------------------------------------------------------------------
// K5: flash-style MFMA neighborhood attention.
// Block = (head, t, 8x8 query tile). 4 waves x 16 queries.
// Per frame a: stage K-union (144x48) and V^T (48x144) bf16 in LDS once for
// all 64 queries; S = Q.K^T via mfma_16x16x32 (dims zero-padded to 64);
// per-query 5x5 window mask in C-layout; online softmax; P -> LDS (C->A
// transform); O += P.V via mfma. Strides 72/168: 16B-aligned, <=2-way banks.
// ---------------------------------------------------------------------------
__global__ __launch_bounds__(256) void attn_kernel(
    const float* __restrict__ qb, const float* __restrict__ kb,
    const float* __restrict__ qkv, unsigned short* __restrict__ A2)
{
    __shared__ unsigned short Ks[144 * 72];   // [key][dim(pad 72, zero 48..71)]
    __shared__ unsigned short Vt[48 * 168];   // [dim][key(pad 168, zero 144..)]
    __shared__ unsigned short Ps[64 * 168];   // [query][key(pad 168, zero 144..)]

    int tid = threadIdx.x;
    int lane = tid & 63, wave = tid >> 6;
    int quad = lane >> 4, l16 = lane & 15;

    int head = blockIdx.x / 27;
    int tile = blockIdx.x - head * 27;
    int tt = tile / 9;
    int sp = tile - tt * 9;
    int h0 = (sp / 3) * 8;
    int w0 = (sp - (sp / 3) * 3) * 8;
    int u0h = min(max(h0 - 2, 0), RES_ - 12);
    int u0w = min(max(w0 - 2, 0), RES_ - 12);

    const float* qbh = qb + (size_t)head * THW_ * DH_;
    const float* kbh = kb + (size_t)head * THW_ * DH_;

    // one-time zero pads
    for (int i = tid; i < 144 * 24; i += 256) {
        int r = i / 24;
        Ks[r * 72 + 48 + (i - r * 24)] = 0;
    }
    for (int i = tid; i < 48 * 24; i += 256) {
        int r = i / 24;
        Vt[r * 168 + 144 + (i - r * 24)] = 0;
    }
    for (int i = tid; i < 64 * 24; i += 256) {
        int r = i / 24;
        Ps[r * 168 + 144 + (i - r * 24)] = 0;
    }

    // Q fragments in registers (same for all 3 frames)
    int qbase = wave * 16;
    bf16x8 qf0, qf1;
    {
        int g = qbase + l16;
        int qtok = tt * HW_ + (h0 + (g >> 3)) * RES_ + (w0 + (g & 7));
        const float* qp = qbh + (size_t)qtok * DH_;
#pragma unroll
        for (int i = 0; i < 8; ++i) qf0[i] = (short)f2bf(qp[quad * 8 + i]);
        if (quad < 2) {
#pragma unroll
            for (int i = 0; i < 8; ++i) qf1[i] = (short)f2bf(qp[32 + quad * 8 + i]);
        } else {
#pragma unroll
            for (int i = 0; i < 8; ++i) qf1[i] = 0;
        }
    }

    // per-row window bounds + per-(nt,r) validity bitmask (frame-independent)
    int vmask[4];
#pragma unroll
    for (int r = 0; r < 4; ++r) {
        int g = qbase + quad * 4 + r;
        int qh = h0 + (g >> 3), qw = w0 + (g & 7);
        int hs = min(max(qh - 2, 0), RES_ - 5);
        int ws = min(max(qw - 2, 0), RES_ - 5);
        int vm = 0;
#pragma unroll
        for (int nt = 0; nt < 9; ++nt) {
            int kk = nt * 16 + l16;
            int hc = u0h + kk / 12;
            int wc = u0w + kk - (kk / 12) * 12;
            int ok = (hc >= hs) & (hc < hs + 5) & (wc >= ws) & (wc < ws + 5);
            vm |= ok << nt;
        }
        vmask[r] = vm;
    }

    float mrow[4] = {-1e30f, -1e30f, -1e30f, -1e30f};
    float lrow[4] = {};
    f32x4 Oacc[3] = {};

    for (int a = 0; a < T_; ++a) {
        // cooperative staging of K (144x48) and V^T (48x144)
        for (int i = tid; i < 144 * 48; i += 256) {
            int kk = i / 48;
            int d = i - kk * 48;
            int hc = u0h + kk / 12;
            int wc = u0w + kk - (kk / 12) * 12;
            int tok = a * HW_ + hc * RES_ + wc;
            Ks[kk * 72 + d] = f2bf(kbh[(size_t)tok * DH_ + d]);
            Vt[d * 168 + kk] =
                f2bf(qkv[(size_t)tok * QKV_ + 1536 + head * DH_ + d]);
        }
        __syncthreads();

        // S = Q.K^T  (9 n-tiles of 16 keys)
        f32x4 sc[9];
#pragma unroll
        for (int nt = 0; nt < 9; ++nt) {
            bf16x8 kf0 = *(const bf16x8*)&Ks[(nt * 16 + l16) * 72 + quad * 8];
            bf16x8 kf1 = *(const bf16x8*)&Ks[(nt * 16 + l16) * 72 + 32 + quad * 8];
            f32x4 z = {};
            z = __builtin_amdgcn_mfma_f32_16x16x32_bf16(qf0, kf0, z, 0, 0, 0);
            sc[nt] = __builtin_amdgcn_mfma_f32_16x16x32_bf16(qf1, kf1, z, 0, 0, 0);
        }

        // mask + online softmax (row = quad*4+r, col = nt*16+l16)
        float rmax[4] = {-1e30f, -1e30f, -1e30f, -1e30f};
#pragma unroll
        for (int nt = 0; nt < 9; ++nt)
#pragma unroll
            for (int r = 0; r < 4; ++r) {
                float s = ((vmask[r] >> nt) & 1) ? sc[nt][r] : -1e30f;
                sc[nt][r] = s;
                rmax[r] = fmaxf(rmax[r], s);
            }
#pragma unroll
        for (int off = 1; off < 16; off <<= 1)
#pragma unroll
            for (int r = 0; r < 4; ++r)
                rmax[r] = fmaxf(rmax[r], __shfl_xor(rmax[r], off));
        float alpha[4], rsum[4] = {};
#pragma unroll
        for (int r = 0; r < 4; ++r) {
            float mn = fmaxf(mrow[r], rmax[r]);
            alpha[r] = expf(mrow[r] - mn);
            mrow[r] = mn;
        }
#pragma unroll
        for (int nt = 0; nt < 9; ++nt)
#pragma unroll
            for (int r = 0; r < 4; ++r) {
                float p = expf(sc[nt][r] - mrow[r]);
                rsum[r] += p;
                Ps[(qbase + quad * 4 + r) * 168 + nt * 16 + l16] = f2bf(p);
            }
#pragma unroll
        for (int off = 1; off < 16; off <<= 1)
#pragma unroll
            for (int r = 0; r < 4; ++r)
                rsum[r] += __shfl_xor(rsum[r], off);
#pragma unroll
        for (int r = 0; r < 4; ++r)
            lrow[r] = lrow[r] * alpha[r] + rsum[r];
#pragma unroll
        for (int vt = 0; vt < 3; ++vt)
#pragma unroll
            for (int r = 0; r < 4; ++r)
                Oacc[vt][r] *= alpha[r];

        // O += P.V  (P rows are wave-private; same-wave LDS RAW is ordered)
#pragma unroll
        for (int ks = 0; ks < 5; ++ks) {
            bf16x8 pf = *(const bf16x8*)&Ps[(qbase + l16) * 168 + ks * 32 + quad * 8];
#pragma unroll
            for (int vt = 0; vt < 3; ++vt) {
                bf16x8 vf = *(const bf16x8*)&Vt[(vt * 16 + l16) * 168 + ks * 32 + quad * 8];
                Oacc[vt] = __builtin_amdgcn_mfma_f32_16x16x32_bf16(pf, vf, Oacc[vt], 0, 0, 0);
            }
        }
        __syncthreads();   // protect Ks/Vt before next frame's staging
    }

    // epilogue: xa -> A2[:, 0:768] bf16  (col = vt*16+l16, row = quad*4+r)
#pragma unroll
    for (int r = 0; r < 4; ++r) {
        int g = qbase + quad * 4 + r;
        int m = tt * HW_ + (h0 + (g >> 3)) * RES_ + (w0 + (g & 7));
        float inv = 1.f / lrow[r];
#pragma unroll
        for (int vt = 0; vt < 3; ++vt) {
            int d = vt * 16 + l16;
            A2[(size_t)m * KTOT_ + head * DH_ + d] = f2bf(Oacc[vt][r] * inv);
        }
    }
}

// ---------------------------------------------------------------------------
// K6: MFMA GEMM2 (split-K=6): P[s] = A2(1792x3840) @ Bt2^T(768x3840), slice s
// ---------------------------------------------------------------------------
__global__ __launch_bounds__(256) void gemm2_kernel(
    const unsigned short* __restrict__ A,   // 1792 x 3840
    const unsigned short* __restrict__ Bt,  // 768 x 3840
    unsigned short* __restrict__ P)         // 6 x 1792 x 768
{
    const int K = KTOT_;
    __shared__ unsigned short As[128 * 32];
    __shared__ unsigned short Bs[128 * 32];
    int tid = threadIdx.x;
    int bm = blockIdx.y * 128;
    int bn = blockIdx.x * 128;
    int ks = blockIdx.z * (KTOT_ / SPLITK_);
    int wave = tid >> 6, lane = tid & 63;
    int quad = lane >> 4, l16 = lane & 15;
    int wm = (wave & 1) * 64;
    int wn = (wave >> 1) * 64;
    f32x4 acc[4][4] = {};
    int srow = tid >> 2;
    int skk  = (tid & 3) * 8;
    const unsigned short* Ag = A + (size_t)(bm + srow) * K + skk;
    const unsigned short* Bg = Bt + (size_t)(bn + srow) * K + skk;
    unsigned short* la0 = &As[srow * 32 + skk];
    unsigned short* la1 = &As[(srow + 64) * 32 + skk];
    unsigned short* lb0 = &Bs[srow * 32 + skk];
    unsigned short* lb1 = &Bs[(srow + 64) * 32 + skk];
    for (int k0 = ks; k0 < ks + KTOT_ / SPLITK_; k0 += 32) {
        async_copy16(Ag + k0, la0);
        async_copy16(Ag + (size_t)64 * K + k0, la1);
        async_copy16(Bg + k0, lb0);
        async_copy16(Bg + (size_t)64 * K + k0, lb1);
        __syncthreads();
        bf16x8 af[4], bf[4];
#pragma unroll
        for (int mt = 0; mt < 4; ++mt)
            af[mt] = *(const bf16x8*)&As[(wm + mt * 16 + l16) * 32 + quad * 8];
#pragma unroll
        for (int nt = 0; nt < 4; ++nt)
            bf[nt] = *(const bf16x8*)&Bs[(wn + nt * 16 + l16) * 32 + quad * 8];
#pragma unroll
        for (int mt = 0; mt < 4; ++mt)
#pragma unroll
            for (int nt = 0; nt < 4; ++nt)
                acc[mt][nt] = __builtin_amdgcn_mfma_f32_16x16x32_bf16(
                    af[mt], bf[nt], acc[mt][nt], 0, 0, 0);
        __syncthreads();
    }
    unsigned short* Pp = P + (size_t)blockIdx.z * MP_ * DIM_;
#pragma unroll
    for (int mt = 0; mt < 4; ++mt) {
#pragma unroll
        for (int nt = 0; nt < 4; ++nt) {
            int gcol = bn + wn + nt * 16 + l16;
#pragma unroll
            for (int r = 0; r < 4; ++r) {
                int grow = bm + wm + mt * 16 + quad * 4 + r;
                if (grow < THW_)
                    Pp[(size_t)grow * DIM_ + gcol] = f2bf(acc[mt][nt][r]);
            }
        }
    }
}

// ---------------------------------------------------------------------------
// K7: out[(t*DIM+n)*HW+hw] = x + b_mlp[n] + sum_s P[s][m][n]
// ---------------------------------------------------------------------------
__global__ __launch_bounds__(256) void reduce_out_kernel(
    const unsigned short* __restrict__ P, const float* __restrict__ x,
    const float* __restrict__ b_mlp, float* __restrict__ out)
{
    __shared__ float tile[32][65];
    int bm = blockIdx.x * 64;
    int bn = blockIdx.y * 32;
    int tid = threadIdx.x;
    int t = bm / HW_;
    int hw0 = bm - t * HW_;
    for (int i = tid; i < 512; i += 256) {
        int ml = i >> 3;
        int n4 = (i & 7) * 4;
        float s0 = 0.f, s1 = 0.f, s2 = 0.f, s3 = 0.f;
#pragma unroll
        for (int sI = 0; sI < SPLITK_; ++sI) {
            const unsigned short* pp =
                P + ((size_t)sI * MP_ + bm + ml) * DIM_ + bn + n4;
            ushort4 u = *(const ushort4*)pp;
            s0 += bf2f(u.x); s1 += bf2f(u.y);
            s2 += bf2f(u.z); s3 += bf2f(u.w);
        }
        tile[n4 + 0][ml] = s0;
        tile[n4 + 1][ml] = s1;
        tile[n4 + 2][ml] = s2;
        tile[n4 + 3][ml] = s3;
    }
    __syncthreads();
    for (int i = tid; i < 512; i += 256) {
        int n = i >> 4;
        int ms = (i & 15) * 4;
        int gn = bn + n;
        size_t base = ((size_t)t * DIM_ + gn) * HW_ + hw0 + ms;
        float bv = b_mlp[gn];
        float4 xv = *(const float4*)(x + base);
        float4 o;
        o.x = xv.x + bv + tile[n][ms + 0];
        o.y = xv.y + bv + tile[n][ms + 1];
        o.z = xv.z + bv + tile[n][ms + 2];
        o.w = xv.w + bv + tile[n][ms + 3];
        *(float4*)(out + base) = o;
    }
}

// ---------------------------------------------------------------------------
extern "C" void kernel_launch(void* const* d_in, const int* in_sizes, int n_in,
                              void* d_out, int out_size, void* d_ws, size_t ws_size,
                              hipStream_t stream) {
    const float* x       = (const float*)d_in[0];
    const float* emb     = (const float*)d_in[1];
    const float* w_mod   = (const float*)d_in[2];
    const float* b_mod   = (const float*)d_in[3];
    const float* qn_w    = (const float*)d_in[4];
    const float* qn_b    = (const float*)d_in[5];
    const float* kn_w    = (const float*)d_in[6];
    const float* kn_b    = (const float*)d_in[7];
    const float* W_fused = (const float*)d_in[8];
    const float* b_fused = (const float*)d_in[9];
    const float* W_out   = (const float*)d_in[10];
    const float* W_mlp   = (const float*)d_in[11];
    const float* b_mlp   = (const float*)d_in[12];
    float* out = (float*)d_out;

    char* w = (char*)d_ws;
    float* mod = (float*)w;            w += (size_t)4608 * 4;
    float* qkv = (float*)w;            w += (size_t)THW_ * QKV_ * 4;
    float* qb  = (float*)w;            w += (size_t)HEADS_ * THW_ * DH_ * 4;
    float* kb  = (float*)w;            w += (size_t)HEADS_ * THW_ * DH_ * 4;
    unsigned short* h   = (unsigned short*)w;  w += (size_t)MP_ * DIM_ * 2;
    unsigned short* A2  = (unsigned short*)w;  w += (size_t)MP_ * KTOT_ * 2;
    unsigned short* Bt1 = (unsigned short*)w;  w += (size_t)NF_ * DIM_ * 2;
    unsigned short* Bt2 = (unsigned short*)w;  w += (size_t)DIM_ * KTOT_ * 2;
    unsigned short* P   = (unsigned short*)w;  w += (size_t)SPLITK_ * MP_ * DIM_ * 2;

    conv_wfused_kernel<<<dim3(NF_ / 32, DIM_ / 32), 256, 0, stream>>>(W_fused, Bt1);
    conv_wcat_kernel<<<dim3(KTOT_ / 32, DIM_ / 32), 256, 0, stream>>>(W_out, W_mlp, Bt2);
    mod_kernel<<<dim3(12, 3), 256, 0, stream>>>(emb, w_mod, b_mod, mod);
    ln_mod_kernel<<<THW_, 256, 0, stream>>>(x, mod, h);
    gemm1_kernel<<<dim3(NF_ / 128, MP_ / 128), 256, 0, stream>>>(h, Bt1, b_fused, qkv, A2);
    qkln_rope_kernel<<<(HEADS_ * THW_) / 4, 256, 0, stream>>>(qkv, qn_w, qn_b, kn_w, kn_b, qb, kb);
    attn_kernel<<<HEADS_ * 27, 256, 0, stream>>>(qb, kb, qkv, A2);
    gemm2_kernel<<<dim3(DIM_ / 128, MP_ / 128, SPLITK_), 256, 0, stream>>>(A2, Bt2, P);
    reduce_out_kernel<<<dim3(THW_ / 64, DIM_ / 32), 256, 0, stream>>>(P, x, b_mlp, out);
}

// Round 5
// 237.961 us; speedup vs baseline: 3.2431x; 1.0405x over previous
//
#include <hip/hip_runtime.h>
#include <hip/hip_bf16.h>
#include <math.h>

#define T_    3
#define RES_  24
#define DIM_  768
#define HEADS_ 16
#define DH_   48
#define EMB_  1024
#define HW_   576            // RES*RES
#define THW_  1728           // T*HW
#define MP_   1792           // THW padded to multiple of 128
#define MLP_  3072
#define NF_   5376           // 3*DIM + MLP
#define QKV_  2304           // 3*DIM
#define QK_   1536           // 2*DIM (q,k only)
#define KTOT_ 3840           // DIM + MLP (second GEMM K)
#define SPLITK_ 6
#define EPS_  1e-5f

typedef __attribute__((ext_vector_type(8))) short bf16x8;
typedef __attribute__((ext_vector_type(4))) float f32x4;

__device__ __forceinline__ float siluf(float x) { return x / (1.f + expf(-x)); }

__device__ __forceinline__ unsigned short f2bf(float f) {
    __hip_bfloat16 b = __float2bfloat16(f);
    return *reinterpret_cast<unsigned short*>(&b);
}

__device__ __forceinline__ float bf2f(unsigned short u) {
    return __uint_as_float(((unsigned)u) << 16);
}

__device__ __forceinline__ void async_copy16(const void* g, void* l) {
    __builtin_amdgcn_global_load_lds(
        (__attribute__((address_space(1))) void*)g,
        (__attribute__((address_space(3))) void*)l,
        16, 0, 0);
}

// ---------------------------------------------------------------------------
// K0a: W_fused (768 x 5376 f32) -> Bt1 (5376 x 768 bf16)   [transposed]
// ---------------------------------------------------------------------------
__global__ __launch_bounds__(256) void conv_wfused_kernel(
    const float* __restrict__ W, unsigned short* __restrict__ Wt)
{
    __shared__ float tile[32][33];
    int n0 = blockIdx.x * 32;
    int k0 = blockIdx.y * 32;
    int c = threadIdx.x & 31;
    int r = threadIdx.x >> 5;
#pragma unroll
    for (int i = 0; i < 4; ++i)
        tile[r + 8 * i][c] = W[(size_t)(k0 + r + 8 * i) * NF_ + n0 + c];
    __syncthreads();
#pragma unroll
    for (int i = 0; i < 4; ++i)
        Wt[(size_t)(n0 + r + 8 * i) * DIM_ + k0 + c] = f2bf(tile[c][r + 8 * i]);
}

// ---------------------------------------------------------------------------
// K0b: [W_out;W_mlp] (3840 x 768 f32) -> Bt2 (768 x 3840 bf16)  [transposed]
// ---------------------------------------------------------------------------
__global__ __launch_bounds__(256) void conv_wcat_kernel(
    const float* __restrict__ W_out, const float* __restrict__ W_mlp,
    unsigned short* __restrict__ Wt)
{
    __shared__ float tile[32][33];
    int k0 = blockIdx.x * 32;
    int n0 = blockIdx.y * 32;
    int c = threadIdx.x & 31;
    int r = threadIdx.x >> 5;
#pragma unroll
    for (int i = 0; i < 4; ++i) {
        int k = k0 + r + 8 * i;
        float v = (k < DIM_) ? W_out[(size_t)k * DIM_ + n0 + c]
                             : W_mlp[(size_t)(k - DIM_) * DIM_ + n0 + c];
        tile[r + 8 * i][c] = v;
    }
    __syncthreads();
#pragma unroll
    for (int i = 0; i < 4; ++i)
        Wt[(size_t)(n0 + r + 8 * i) * KTOT_ + k0 + c] = f2bf(tile[c][r + 8 * i]);
}

// ---------------------------------------------------------------------------
// K1: mod[t][j] = silu(emb[t]) @ w_mod + b_mod   (3 x 1536)
// ---------------------------------------------------------------------------
__global__ __launch_bounds__(256) void mod_kernel(
    const float* __restrict__ emb, const float* __restrict__ w_mod,
    const float* __restrict__ b_mod, float* __restrict__ mod)
{
    int t = blockIdx.y;
    int chunk = blockIdx.x;
    __shared__ float se[EMB_];
    __shared__ float part[128];
    int tid = threadIdx.x;
    for (int i = tid; i < EMB_; i += 256) {
        float e = emb[t * EMB_ + i];
        se[i] = e / (1.f + expf(-e));
    }
    __syncthreads();
    int r = tid >> 7;
    int c = tid & 127;
    int j = chunk * 128 + c;
    const float* wp = w_mod + j;
    float acc = 0.f;
    for (int e = r * 512; e < r * 512 + 512; ++e)
        acc += se[e] * wp[e * 1536];
    if (r == 1) part[c] = acc;
    __syncthreads();
    if (r == 0)
        mod[t * 1536 + j] = acc + part[c] + b_mod[j];
}

// ---------------------------------------------------------------------------
// K2: LN+modulate, 4 tokens per block (float4 loads along hw; hw0 4-aligned,
// never crosses a t boundary since 576 % 4 == 0)
// ---------------------------------------------------------------------------
__global__ __launch_bounds__(256) void ln_mod_kernel(
    const float* __restrict__ x, const float* __restrict__ mod,
    unsigned short* __restrict__ h)
{
    int m0 = blockIdx.x * 4;
    int t = m0 / HW_;
    int hw0 = m0 - t * HW_;
    const float* xp = x + (size_t)t * DIM_ * HW_ + hw0;
    int tid = threadIdx.x;
    float4 X0 = *(const float4*)(xp + (size_t)tid * HW_);
    float4 X1 = *(const float4*)(xp + (size_t)(tid + 256) * HW_);
    float4 X2 = *(const float4*)(xp + (size_t)(tid + 512) * HW_);
    float4 sv, sqv;
    sv.x = X0.x + X1.x + X2.x;  sv.y = X0.y + X1.y + X2.y;
    sv.z = X0.z + X1.z + X2.z;  sv.w = X0.w + X1.w + X2.w;
    sqv.x = X0.x*X0.x + X1.x*X1.x + X2.x*X2.x;
    sqv.y = X0.y*X0.y + X1.y*X1.y + X2.y*X2.y;
    sqv.z = X0.z*X0.z + X1.z*X1.z + X2.z*X2.z;
    sqv.w = X0.w*X0.w + X1.w*X1.w + X2.w*X2.w;
#pragma unroll
    for (int off = 32; off > 0; off >>= 1) {
        sv.x += __shfl_xor(sv.x, off, 64);  sv.y += __shfl_xor(sv.y, off, 64);
        sv.z += __shfl_xor(sv.z, off, 64);  sv.w += __shfl_xor(sv.w, off, 64);
        sqv.x += __shfl_xor(sqv.x, off, 64); sqv.y += __shfl_xor(sqv.y, off, 64);
        sqv.z += __shfl_xor(sqv.z, off, 64); sqv.w += __shfl_xor(sqv.w, off, 64);
    }
    __shared__ float4 ssum[4], ssq[4];
    int lane = tid & 63, wid = tid >> 6;
    if (lane == 0) { ssum[wid] = sv; ssq[wid] = sqv; }
    __syncthreads();
    float mean[4], rs[4];
#pragma unroll
    for (int j = 0; j < 4; ++j) {
        float tot  = ((const float*)&ssum[0])[j] + ((const float*)&ssum[1])[j]
                   + ((const float*)&ssum[2])[j] + ((const float*)&ssum[3])[j];
        float totq = ((const float*)&ssq[0])[j] + ((const float*)&ssq[1])[j]
                   + ((const float*)&ssq[2])[j] + ((const float*)&ssq[3])[j];
        float mn = tot * (1.f / 768.f);
        float var = totq * (1.f / 768.f) - mn * mn;
        mean[j] = mn;
        rs[j] = rsqrtf(var + EPS_);
    }
    const float* sc = mod + t * 1536;
    const float* sh = sc + 768;
#pragma unroll
    for (int cc = 0; cc < 3; ++cc) {
        int c = tid + cc * 256;
        float4 X = (cc == 0) ? X0 : (cc == 1) ? X1 : X2;
        float scl = 1.f + sc[c];
        float shf = sh[c];
        const float* Xp = (const float*)&X;
#pragma unroll
        for (int j = 0; j < 4; ++j)
            h[(size_t)(m0 + j) * DIM_ + c] =
                f2bf((Xp[j] - mean[j]) * rs[j] * scl + shf);
    }
}

// ---------------------------------------------------------------------------
// K3: MFMA GEMM1: C = h(1792x768) @ Bt1^T(5376x768) + b_fused
// epilogue: col<1536 -> qkv fp32 (q,k); col<2304 -> vb bf16; else silu->A2
// ---------------------------------------------------------------------------
__global__ __launch_bounds__(256) void gemm1_kernel(
    const unsigned short* __restrict__ A,   // 1792 x 768
    const unsigned short* __restrict__ Bt,  // 5376 x 768
    const float* __restrict__ bias,
    float* __restrict__ qkv,                // 1728 x 1536 (q,k)
    unsigned short* __restrict__ vb,        // 1728 x 768 (v, bf16)
    unsigned short* __restrict__ A2)        // 1792 x 3840
{
    const int K = DIM_;
    __shared__ unsigned short As[128 * 32];
    __shared__ unsigned short Bs[128 * 32];
    int tid = threadIdx.x;
    int bm = blockIdx.y * 128;
    int bn = blockIdx.x * 128;
    int wave = tid >> 6, lane = tid & 63;
    int quad = lane >> 4, l16 = lane & 15;
    int wm = (wave & 1) * 64;
    int wn = (wave >> 1) * 64;
    f32x4 acc[4][4] = {};
    int srow = tid >> 2;
    int skk  = (tid & 3) * 8;
    const unsigned short* Ag = A + (size_t)(bm + srow) * K + skk;
    const unsigned short* Bg = Bt + (size_t)(bn + srow) * K + skk;
    unsigned short* la0 = &As[srow * 32 + skk];
    unsigned short* la1 = &As[(srow + 64) * 32 + skk];
    unsigned short* lb0 = &Bs[srow * 32 + skk];
    unsigned short* lb1 = &Bs[(srow + 64) * 32 + skk];
    for (int k0 = 0; k0 < K; k0 += 32) {
        async_copy16(Ag + k0, la0);
        async_copy16(Ag + (size_t)64 * K + k0, la1);
        async_copy16(Bg + k0, lb0);
        async_copy16(Bg + (size_t)64 * K + k0, lb1);
        __syncthreads();
        bf16x8 af[4], bf[4];
#pragma unroll
        for (int mt = 0; mt < 4; ++mt)
            af[mt] = *(const bf16x8*)&As[(wm + mt * 16 + l16) * 32 + quad * 8];
#pragma unroll
        for (int nt = 0; nt < 4; ++nt)
            bf[nt] = *(const bf16x8*)&Bs[(wn + nt * 16 + l16) * 32 + quad * 8];
#pragma unroll
        for (int mt = 0; mt < 4; ++mt)
#pragma unroll
            for (int nt = 0; nt < 4; ++nt)
                acc[mt][nt] = __builtin_amdgcn_mfma_f32_16x16x32_bf16(
                    af[mt], bf[nt], acc[mt][nt], 0, 0, 0);
        __syncthreads();
    }
#pragma unroll
    for (int mt = 0; mt < 4; ++mt) {
#pragma unroll
        for (int nt = 0; nt < 4; ++nt) {
            int gcol = bn + wn + nt * 16 + l16;
            float b = bias[gcol];
#pragma unroll
            for (int r = 0; r < 4; ++r) {
                int grow = bm + wm + mt * 16 + quad * 4 + r;
                if (grow < THW_) {
                    float v = acc[mt][nt][r] + b;
                    if (gcol < QK_)
                        qkv[(size_t)grow * QK_ + gcol] = v;
                    else if (gcol < QKV_)
                        vb[(size_t)grow * DIM_ + (gcol - QK_)] = f2bf(v);
                    else
                        A2[(size_t)grow * KTOT_ + (gcol - QKV_ + DIM_)] = f2bf(siluf(v));
                }
            }
        }
    }
}

// ---------------------------------------------------------------------------
// K4: per (head, token) wave: LN(q), LN(k) over DH=48, RoPE, q*=1/sqrt(48)
// outputs bf16 [head][token][48]
// ---------------------------------------------------------------------------
__global__ __launch_bounds__(256) void qkln_rope_kernel(
    const float* __restrict__ qkv,
    const float* __restrict__ qn_w, const float* __restrict__ qn_b,
    const float* __restrict__ kn_w, const float* __restrict__ kn_b,
    unsigned short* __restrict__ qb, unsigned short* __restrict__ kb)
{
    int tid = threadIdx.x;
    int lane = tid & 63, wid = tid >> 6;
    int idx = blockIdx.x * 4 + wid;
    int head = idx / THW_;
    int m = idx - head * THW_;
    const float* fp = qkv + (size_t)m * QK_ + head * DH_;
    float qv = 0.f, kv = 0.f;
    if (lane < DH_) { qv = fp[lane]; kv = fp[768 + lane]; }
    float s = qv, sq = qv * qv, sk = kv, sqk = kv * kv;
#pragma unroll
    for (int off = 32; off > 0; off >>= 1) {
        s   += __shfl_xor(s, off, 64);
        sq  += __shfl_xor(sq, off, 64);
        sk  += __shfl_xor(sk, off, 64);
        sqk += __shfl_xor(sqk, off, 64);
    }
    float mq = s  * (1.f / 48.f), vq = sq  * (1.f / 48.f) - mq * mq;
    float mk = sk * (1.f / 48.f), vk = sqk * (1.f / 48.f) - mk * mk;
    float qn = 0.f, kn = 0.f;
    if (lane < DH_) {
        qn = (qv - mq) * rsqrtf(vq + EPS_) * qn_w[lane] + qn_b[lane];
        kn = (kv - mk) * rsqrtf(vk + EPS_) * kn_w[lane] + kn_b[lane];
    }
    int t = m / HW_; int hw = m - t * HW_;
    int hh = hw / RES_; int ww = hw - hh * RES_;
    int i = lane >> 1;
    int grp = i >> 3, j = i & 7;
    float pos = (grp == 0) ? (float)t : (grp == 1) ? (float)hh : (float)ww;
    float invf = exp2f(-1.6609640474436813f * (float)j);   // 10000^(-j/8)
    float ang = pos * invf;
    float cs = cosf(ang), sn = sinf(ang);
    float qp = __shfl_xor(qn, 1, 64);
    float kp = __shfl_xor(kn, 1, 64);
    float qo, ko;
    if ((lane & 1) == 0) { qo = qn * cs - qp * sn; ko = kn * cs - kp * sn; }
    else                 { qo = qp * sn + qn * cs; ko = kp * sn + kn * cs; }
    if (lane < DH_) {
        size_t o = ((size_t)head * THW_ + m) * DH_ + lane;
        qb[o] = f2bf(qo * 0.14433756729740643f);
        kb[o] = f2bf(ko);
    }
}

// ---------------------------------------------------------------------------
// K5: flash-style MFMA neighborhood attention (all-bf16 inputs).
// Block = (head, t, 8x8 query tile). 4 waves x 16 queries.
// ---------------------------------------------------------------------------
__global__ __launch_bounds__(256) void attn_kernel(
    const unsigned short* __restrict__ qb, const unsigned short* __restrict__ kb,
    const unsigned short* __restrict__ vb, unsigned short* __restrict__ A2)
{
    __shared__ unsigned short Ks[144 * 72];   // [key][dim(pad 72, zero 48..71)]
    __shared__ unsigned short Vt[48 * 168];   // [dim][key(pad 168, zero 144..)]
    __shared__ unsigned short Ps[64 * 168];   // [query][key(pad 168, zero 144..)]

    int tid = threadIdx.x;
    int lane = tid & 63, wave = tid >> 6;
    int quad = lane >> 4, l16 = lane & 15;

    int head = blockIdx.x / 27;
    int tile = blockIdx.x - head * 27;
    int tt = tile / 9;
    int sp = tile - tt * 9;
    int h0 = (sp / 3) * 8;
    int w0 = (sp - (sp / 3) * 3) * 8;
    int u0h = min(max(h0 - 2, 0), RES_ - 12);
    int u0w = min(max(w0 - 2, 0), RES_ - 12);

    const unsigned short* qbh = qb + (size_t)head * THW_ * DH_;
    const unsigned short* kbh = kb + (size_t)head * THW_ * DH_;
    const unsigned short* vbh = vb + head * DH_;

    // one-time zero pads
    for (int i = tid; i < 144 * 24; i += 256) {
        int r = i / 24;
        Ks[r * 72 + 48 + (i - r * 24)] = 0;
    }
    for (int i = tid; i < 48 * 24; i += 256) {
        int r = i / 24;
        Vt[r * 168 + 144 + (i - r * 24)] = 0;
    }
    for (int i = tid; i < 64 * 24; i += 256) {
        int r = i / 24;
        Ps[r * 168 + 144 + (i - r * 24)] = 0;
    }

    // Q fragments: direct bf16x8 loads (row = 96 B, 16B-aligned)
    int qbase = wave * 16;
    bf16x8 qf0, qf1;
    {
        int g = qbase + l16;
        int qtok = tt * HW_ + (h0 + (g >> 3)) * RES_ + (w0 + (g & 7));
        const unsigned short* qp = qbh + (size_t)qtok * DH_;
        qf0 = *(const bf16x8*)(qp + quad * 8);
        if (quad < 2) qf1 = *(const bf16x8*)(qp + 32 + quad * 8);
        else {
#pragma unroll
            for (int i = 0; i < 8; ++i) qf1[i] = 0;
        }
    }

    // per-(r,nt) validity bitmask (frame-independent)
    int vmask[4];
#pragma unroll
    for (int r = 0; r < 4; ++r) {
        int g = qbase + quad * 4 + r;
        int qh = h0 + (g >> 3), qw = w0 + (g & 7);
        int hs = min(max(qh - 2, 0), RES_ - 5);
        int ws = min(max(qw - 2, 0), RES_ - 5);
        int vm = 0;
#pragma unroll
        for (int nt = 0; nt < 9; ++nt) {
            int kk = nt * 16 + l16;
            int hc = u0h + kk / 12;
            int wc = u0w + kk - (kk / 12) * 12;
            int ok = (hc >= hs) & (hc < hs + 5) & (wc >= ws) & (wc < ws + 5);
            vm |= ok << nt;
        }
        vmask[r] = vm;
    }

    float mrow[4] = {-1e30f, -1e30f, -1e30f, -1e30f};
    float lrow[4] = {};
    f32x4 Oacc[3] = {};

    for (int a = 0; a < T_; ++a) {
        // cooperative staging: K (144x48) ushort4, V^T (48x144) transposed
        for (int i = tid; i < 144 * 12; i += 256) {
            int kk = i / 12;
            int g = i - kk * 12;          // dim group: dims 4g..4g+3
            int hc = u0h + kk / 12;
            int wc = u0w + kk - (kk / 12) * 12;
            int tok = a * HW_ + hc * RES_ + wc;
            ushort4 k4 = *(const ushort4*)(kbh + (size_t)tok * DH_ + 4 * g);
            *(ushort4*)&Ks[kk * 72 + 4 * g] = k4;
            ushort4 v4 = *(const ushort4*)(vbh + (size_t)tok * DIM_ + 4 * g);
            Vt[(4 * g + 0) * 168 + kk] = v4.x;
            Vt[(4 * g + 1) * 168 + kk] = v4.y;
            Vt[(4 * g + 2) * 168 + kk] = v4.z;
            Vt[(4 * g + 3) * 168 + kk] = v4.w;
        }
        __syncthreads();

        // S = Q.K^T  (9 n-tiles of 16 keys)
        f32x4 sc[9];
#pragma unroll
        for (int nt = 0; nt < 9; ++nt) {
            bf16x8 kf0 = *(const bf16x8*)&Ks[(nt * 16 + l16) * 72 + quad * 8];
            bf16x8 kf1 = *(const bf16x8*)&Ks[(nt * 16 + l16) * 72 + 32 + quad * 8];
            f32x4 z = {};
            z = __builtin_amdgcn_mfma_f32_16x16x32_bf16(qf0, kf0, z, 0, 0, 0);
            sc[nt] = __builtin_amdgcn_mfma_f32_16x16x32_bf16(qf1, kf1, z, 0, 0, 0);
        }

        // mask + online softmax (row = quad*4+r, col = nt*16+l16)
        float rmax[4] = {-1e30f, -1e30f, -1e30f, -1e30f};
#pragma unroll
        for (int nt = 0; nt < 9; ++nt)
#pragma unroll
            for (int r = 0; r < 4; ++r) {
                float s = ((vmask[r] >> nt) & 1) ? sc[nt][r] : -1e30f;
                sc[nt][r] = s;
                rmax[r] = fmaxf(rmax[r], s);
            }
#pragma unroll
        for (int off = 1; off < 16; off <<= 1)
#pragma unroll
            for (int r = 0; r < 4; ++r)
                rmax[r] = fmaxf(rmax[r], __shfl_xor(rmax[r], off));
        float alpha[4], rsum[4] = {};
#pragma unroll
        for (int r = 0; r < 4; ++r) {
            float mn = fmaxf(mrow[r], rmax[r]);
            alpha[r] = expf(mrow[r] - mn);
            mrow[r] = mn;
        }
#pragma unroll
        for (int nt = 0; nt < 9; ++nt)
#pragma unroll
            for (int r = 0; r < 4; ++r) {
                float p = expf(sc[nt][r] - mrow[r]);
                rsum[r] += p;
                Ps[(qbase + quad * 4 + r) * 168 + nt * 16 + l16] = f2bf(p);
            }
#pragma unroll
        for (int off = 1; off < 16; off <<= 1)
#pragma unroll
            for (int r = 0; r < 4; ++r)
                rsum[r] += __shfl_xor(rsum[r], off);
#pragma unroll
        for (int r = 0; r < 4; ++r)
            lrow[r] = lrow[r] * alpha[r] + rsum[r];
#pragma unroll
        for (int vt = 0; vt < 3; ++vt)
#pragma unroll
            for (int r = 0; r < 4; ++r)
                Oacc[vt][r] *= alpha[r];

        // O += P.V  (P rows wave-private; same-wave LDS RAW is ordered)
#pragma unroll
        for (int ks = 0; ks < 5; ++ks) {
            bf16x8 pf = *(const bf16x8*)&Ps[(qbase + l16) * 168 + ks * 32 + quad * 8];
#pragma unroll
            for (int vt = 0; vt < 3; ++vt) {
                bf16x8 vf = *(const bf16x8*)&Vt[(vt * 16 + l16) * 168 + ks * 32 + quad * 8];
                Oacc[vt] = __builtin_amdgcn_mfma_f32_16x16x32_bf16(pf, vf, Oacc[vt], 0, 0, 0);
            }
        }
        __syncthreads();   // protect Ks/Vt before next frame's staging
    }

    // epilogue: xa -> A2[:, 0:768] bf16
#pragma unroll
    for (int r = 0; r < 4; ++r) {
        int g = qbase + quad * 4 + r;
        int m = tt * HW_ + (h0 + (g >> 3)) * RES_ + (w0 + (g & 7));
        float inv = 1.f / lrow[r];
#pragma unroll
        for (int vt = 0; vt < 3; ++vt) {
            int d = vt * 16 + l16;
            A2[(size_t)m * KTOT_ + head * DH_ + d] = f2bf(Oacc[vt][r] * inv);
        }
    }
}

// ---------------------------------------------------------------------------
// K6: MFMA GEMM2 (split-K=6): P[s] = A2(1792x3840) @ Bt2^T(768x3840), slice s
// ---------------------------------------------------------------------------
__global__ __launch_bounds__(256) void gemm2_kernel(
    const unsigned short* __restrict__ A,   // 1792 x 3840
    const unsigned short* __restrict__ Bt,  // 768 x 3840
    unsigned short* __restrict__ P)         // 6 x 1792 x 768
{
    const int K = KTOT_;
    __shared__ unsigned short As[128 * 32];
    __shared__ unsigned short Bs[128 * 32];
    int tid = threadIdx.x;
    int bm = blockIdx.y * 128;
    int bn = blockIdx.x * 128;
    int ks = blockIdx.z * (KTOT_ / SPLITK_);
    int wave = tid >> 6, lane = tid & 63;
    int quad = lane >> 4, l16 = lane & 15;
    int wm = (wave & 1) * 64;
    int wn = (wave >> 1) * 64;
    f32x4 acc[4][4] = {};
    int srow = tid >> 2;
    int skk  = (tid & 3) * 8;
    const unsigned short* Ag = A + (size_t)(bm + srow) * K + skk;
    const unsigned short* Bg = Bt + (size_t)(bn + srow) * K + skk;
    unsigned short* la0 = &As[srow * 32 + skk];
    unsigned short* la1 = &As[(srow + 64) * 32 + skk];
    unsigned short* lb0 = &Bs[srow * 32 + skk];
    unsigned short* lb1 = &Bs[(srow + 64) * 32 + skk];
    for (int k0 = ks; k0 < ks + KTOT_ / SPLITK_; k0 += 32) {
        async_copy16(Ag + k0, la0);
        async_copy16(Ag + (size_t)64 * K + k0, la1);
        async_copy16(Bg + k0, lb0);
        async_copy16(Bg + (size_t)64 * K + k0, lb1);
        __syncthreads();
        bf16x8 af[4], bf[4];
#pragma unroll
        for (int mt = 0; mt < 4; ++mt)
            af[mt] = *(const bf16x8*)&As[(wm + mt * 16 + l16) * 32 + quad * 8];
#pragma unroll
        for (int nt = 0; nt < 4; ++nt)
            bf[nt] = *(const bf16x8*)&Bs[(wn + nt * 16 + l16) * 32 + quad * 8];
#pragma unroll
        for (int mt = 0; mt < 4; ++mt)
#pragma unroll
            for (int nt = 0; nt < 4; ++nt)
                acc[mt][nt] = __builtin_amdgcn_mfma_f32_16x16x32_bf16(
                    af[mt], bf[nt], acc[mt][nt], 0, 0, 0);
        __syncthreads();
    }
    unsigned short* Pp = P + (size_t)blockIdx.z * MP_ * DIM_;
#pragma unroll
    for (int mt = 0; mt < 4; ++mt) {
#pragma unroll
        for (int nt = 0; nt < 4; ++nt) {
            int gcol = bn + wn + nt * 16 + l16;
#pragma unroll
            for (int r = 0; r < 4; ++r) {
                int grow = bm + wm + mt * 16 + quad * 4 + r;
                if (grow < THW_)
                    Pp[(size_t)grow * DIM_ + gcol] = f2bf(acc[mt][nt][r]);
            }
        }
    }
}

// ---------------------------------------------------------------------------
// K7: out[(t*DIM+n)*HW+hw] = x + b_mlp[n] + sum_s P[s][m][n]
// ---------------------------------------------------------------------------
__global__ __launch_bounds__(256) void reduce_out_kernel(
    const unsigned short* __restrict__ P, const float* __restrict__ x,
    const float* __restrict__ b_mlp, float* __restrict__ out)
{
    __shared__ float tile[32][65];
    int bm = blockIdx.x * 64;
    int bn = blockIdx.y * 32;
    int tid = threadIdx.x;
    int t = bm / HW_;
    int hw0 = bm - t * HW_;
    for (int i = tid; i < 512; i += 256) {
        int ml = i >> 3;
        int n4 = (i & 7) * 4;
        float s0 = 0.f, s1 = 0.f, s2 = 0.f, s3 = 0.f;
#pragma unroll
        for (int sI = 0; sI < SPLITK_; ++sI) {
            const unsigned short* pp =
                P + ((size_t)sI * MP_ + bm + ml) * DIM_ + bn + n4;
            ushort4 u = *(const ushort4*)pp;
            s0 += bf2f(u.x); s1 += bf2f(u.y);
            s2 += bf2f(u.z); s3 += bf2f(u.w);
        }
        tile[n4 + 0][ml] = s0;
        tile[n4 + 1][ml] = s1;
        tile[n4 + 2][ml] = s2;
        tile[n4 + 3][ml] = s3;
    }
    __syncthreads();
    for (int i = tid; i < 512; i += 256) {
        int n = i >> 4;
        int ms = (i & 15) * 4;
        int gn = bn + n;
        size_t base = ((size_t)t * DIM_ + gn) * HW_ + hw0 + ms;
        float bv = b_mlp[gn];
        float4 xv = *(const float4*)(x + base);
        float4 o;
        o.x = xv.x + bv + tile[n][ms + 0];
        o.y = xv.y + bv + tile[n][ms + 1];
        o.z = xv.z + bv + tile[n][ms + 2];
        o.w = xv.w + bv + tile[n][ms + 3];
        *(float4*)(out + base) = o;
    }
}

// ---------------------------------------------------------------------------
extern "C" void kernel_launch(void* const* d_in, const int* in_sizes, int n_in,
                              void* d_out, int out_size, void* d_ws, size_t ws_size,
                              hipStream_t stream) {
    const float* x       = (const float*)d_in[0];
    const float* emb     = (const float*)d_in[1];
    const float* w_mod   = (const float*)d_in[2];
    const float* b_mod   = (const float*)d_in[3];
    const float* qn_w    = (const float*)d_in[4];
    const float* qn_b    = (const float*)d_in[5];
    const float* kn_w    = (const float*)d_in[6];
    const float* kn_b    = (const float*)d_in[7];
    const float* W_fused = (const float*)d_in[8];
    const float* b_fused = (const float*)d_in[9];
    const float* W_out   = (const float*)d_in[10];
    const float* W_mlp   = (const float*)d_in[11];
    const float* b_mlp   = (const float*)d_in[12];
    float* out = (float*)d_out;

    char* w = (char*)d_ws;
    float* mod = (float*)w;            w += (size_t)4608 * 4;
    float* qkv = (float*)w;            w += (size_t)THW_ * QK_ * 4;
    unsigned short* vb  = (unsigned short*)w;  w += (size_t)THW_ * DIM_ * 2;
    unsigned short* qb  = (unsigned short*)w;  w += (size_t)HEADS_ * THW_ * DH_ * 2;
    unsigned short* kb  = (unsigned short*)w;  w += (size_t)HEADS_ * THW_ * DH_ * 2;
    unsigned short* h   = (unsigned short*)w;  w += (size_t)MP_ * DIM_ * 2;
    unsigned short* A2  = (unsigned short*)w;  w += (size_t)MP_ * KTOT_ * 2;
    unsigned short* Bt1 = (unsigned short*)w;  w += (size_t)NF_ * DIM_ * 2;
    unsigned short* Bt2 = (unsigned short*)w;  w += (size_t)DIM_ * KTOT_ * 2;
    unsigned short* P   = (unsigned short*)w;  w += (size_t)SPLITK_ * MP_ * DIM_ * 2;

    conv_wfused_kernel<<<dim3(NF_ / 32, DIM_ / 32), 256, 0, stream>>>(W_fused, Bt1);
    conv_wcat_kernel<<<dim3(KTOT_ / 32, DIM_ / 32), 256, 0, stream>>>(W_out, W_mlp, Bt2);
    mod_kernel<<<dim3(12, 3), 256, 0, stream>>>(emb, w_mod, b_mod, mod);
    ln_mod_kernel<<<THW_ / 4, 256, 0, stream>>>(x, mod, h);
    gemm1_kernel<<<dim3(NF_ / 128, MP_ / 128), 256, 0, stream>>>(h, Bt1, b_fused, qkv, vb, A2);
    qkln_rope_kernel<<<(HEADS_ * THW_) / 4, 256, 0, stream>>>(qkv, qn_w, qn_b, kn_w, kn_b, qb, kb);
    attn_kernel<<<HEADS_ * 27, 256, 0, stream>>>(qb, kb, vb, A2);
    gemm2_kernel<<<dim3(DIM_ / 128, MP_ / 128, SPLITK_), 256, 0, stream>>>(A2, Bt2, P);
    reduce_out_kernel<<<dim3(THW_ / 64, DIM_ / 32), 256, 0, stream>>>(P, x, b_mlp, out);
}